// Round 3
// baseline (4085.256 us; speedup 1.0000x reference)
//
#include <hip/hip_runtime.h>
#include <hip/hip_bf16.h>
#include <math.h>

#define E_N 1048576
#define CF 47
#define H 128
#define H2 256
#define B_N 64
#define V_N 2048
#define K_N 128
#define N_N 131072
#define EPSf 1e-5f
#define EVS 132   // padded LDS leading dim for fp32 tiles

typedef __attribute__((ext_vector_type(8))) short short8;
typedef __attribute__((ext_vector_type(4))) float f32x4;

__device__ __forceinline__ float bf2f(unsigned int u16) {
  union { float f; unsigned int i; } x; x.i = u16 << 16; return x.f;
}
__device__ __forceinline__ unsigned int f2bf_rne(float f) {
  unsigned int u = __float_as_uint(f);
  return (u + 0x7fffu + ((u >> 16) & 1u)) >> 16;
}
__device__ __forceinline__ unsigned int packbf2(float lo, float hi) {
  return f2bf_rne(lo) | (f2bf_rne(hi) << 16);
}
__device__ __forceinline__ float frcp_(float x) { return __builtin_amdgcn_rcpf(x); }
__device__ __forceinline__ float sigmf_(float x) { return frcp_(1.f + __expf(-x)); }
__device__ __forceinline__ float siluf_(float x) { return x * sigmf_(x); }
__device__ __forceinline__ float splusf_(float x) {
  return (x > 15.f) ? x : __logf(1.f + __expf(x));
}

// ---------------- Stage 1: x1 = chem @ w1 + b1 (E x 128), fused column stats ----------------
// Column-stationary, scalar-A design: thread owns column c (w1 column in 47 VGPRs) and a
// 64-row half. chem row addresses are wave-uniform -> compiler emits s_load (SMEM pipe),
// so the FMA stream has ZERO LDS traffic and no VALU address math. Two accumulator chains
// (even/odd k) for dep-chain ILP. Stats + bias + bf16 pack fused.
extern "C" __global__ __launch_bounds__(256) void k_gemm1_stats(
    const float* __restrict__ chem, const float* __restrict__ w1,
    const float* __restrict__ b1, __hip_bfloat16* __restrict__ x1,
    float* __restrict__ sum1, float* __restrict__ ssq1)
{
  __shared__ float cs[128], cq[128];
  const int tid = threadIdx.x;
  const int c = tid & 127;           // owned output column
  const int half = tid >> 7;         // row half (0: rows 0-63, 1: rows 64-127)
  float wreg[CF];
  #pragma unroll
  for (int k = 0; k < CF; ++k) wreg[k] = w1[k * H + c];
  const float bc = b1[c];
  if (tid < 128) { cs[tid] = 0.f; cq[tid] = 0.f; }
  __syncthreads();

  const int rowbase = blockIdx.x * 128 + half * 64;
  unsigned short* x1s = (unsigned short*)x1;
  float s = 0.f, q = 0.f;
  for (int r = 0; r < 64; ++r) {
    const float* __restrict__ ar = chem + (size_t)(rowbase + r) * CF;  // wave-uniform
    float a0 = bc, a1 = 0.f;
    #pragma unroll
    for (int k = 0; k < CF - 1; k += 2) {
      a0 += ar[k]     * wreg[k];
      a1 += ar[k + 1] * wreg[k + 1];
    }
    a0 += ar[CF - 1] * wreg[CF - 1];
    const float v = a0 + a1;
    s += v;
    q += v * v;
    x1s[(size_t)(rowbase + r) * H + c] = (unsigned short)f2bf_rne(v);
  }
  atomicAdd(&cs[c], s);
  atomicAdd(&cq[c], q);
  __syncthreads();
  if (tid < 128) {
    atomicAdd(&sum1[tid], cs[tid]);
    atomicAdd(&ssq1[tid], cq[tid]);
  }
}

// BN finalize: scale/shift from sum/sumsq (biased var, matches jnp.var)
extern "C" __global__ void k_bnfin(const float* __restrict__ sum, const float* __restrict__ ssq,
    const float* __restrict__ g, const float* __restrict__ be, float invn,
    float* __restrict__ sc, float* __restrict__ sh)
{
  const int c = threadIdx.x;
  const float m = sum[c] * invn;
  const float v = ssq[c] * invn - m * m;
  const float s = g[c] * rsqrtf(v + EPSf);
  sc[c] = s;
  sh[c] = be[c] - m * s;
}

// ---------------- a1 = silu(bn1(x1)); Gram G = a1^T a1 via MFMA; writes a1 (bf16) back IN-PLACE ----
// Per tile (128 rows): each thread stages an 8x8 block (global uint4 reads, in-register
// 8x8 bf16 transpose), writes MFMA-fragment-layout LDS (b128, bank-rotated by pos=(cm+2t)&15).
// frag elem idx = kb*4096 + t*512 + q*128 + pos*8 + j8  holds a1[kb*32+q*8+j8][t*16+cm].
// A- and B-operand layouts of 16x16x32 coincide, so frag(t) serves both sides of G = a^T a.
extern "C" __global__ __launch_bounds__(256) void k_a1_gram(
    __hip_bfloat16* __restrict__ x1, const float* __restrict__ sc1,
    const float* __restrict__ sh1, float* __restrict__ asum, float* __restrict__ G)
{
  __shared__ __align__(16) unsigned short frag[2][16384];   // 2 x 32 KB, double-buffered
  const int tid = threadIdx.x;
  // stage-side ids: thread owns rows [rb*8, rb*8+8) x cols [u*8, u*8+8)
  const int rb = tid >> 4, u = tid & 15;
  const int kb = rb >> 2, qw = rb & 3;
  const int th = u >> 1;                 // subtile column group 0..7
  const int cmb = (u & 1) * 8;
  const int cg = u * 8;
  // MFMA-side ids
  const int w = tid >> 6;
  const int lq = (tid >> 4) & 3;         // lane>>4 within wave
  const int cm = tid & 15;               // lane&15
  const int tib = (w >> 1) * 4, tjb = (w & 1) * 4;   // wave's 4x4 block of 16x16 G-tiles

  float scv[8], shv[8];
  #pragma unroll
  for (int jc = 0; jc < 8; ++jc) { scv[jc] = sc1[cg + jc]; shv[jc] = sh1[cg + jc]; }

  float cs8[8] = {0.f, 0.f, 0.f, 0.f, 0.f, 0.f, 0.f, 0.f};
  f32x4 acc[4][4];
  #pragma unroll
  for (int a = 0; a < 4; ++a)
    #pragma unroll
    for (int b = 0; b < 4; ++b) acc[a][b] = (f32x4){0.f, 0.f, 0.f, 0.f};

  const int ldsbase = kb * 4096 + th * 512 + qw * 128;
  uint4 rv[8];

  // silu + colsum + bf16 pack + global write-back + frag-LDS write of the 8x8 block in rv
  auto PROCESS = [&](int bsel, size_t tb) {
    unsigned int colw[8][4];
    #pragma unroll
    for (int jc = 0; jc < 8; ++jc) { colw[jc][0] = 0; colw[jc][1] = 0; colw[jc][2] = 0; colw[jc][3] = 0; }
    #pragma unroll
    for (int j8 = 0; j8 < 8; ++j8) {
      const uint4 pk = rv[j8];
      float f[8];
      f[0] = bf2f(pk.x & 0xffff); f[1] = bf2f(pk.x >> 16);
      f[2] = bf2f(pk.y & 0xffff); f[3] = bf2f(pk.y >> 16);
      f[4] = bf2f(pk.z & 0xffff); f[5] = bf2f(pk.z >> 16);
      f[6] = bf2f(pk.w & 0xffff); f[7] = bf2f(pk.w >> 16);
      unsigned int bfv[8];
      #pragma unroll
      for (int jc = 0; jc < 8; ++jc) {
        f[jc] = siluf_(f[jc] * scv[jc] + shv[jc]);
        cs8[jc] += f[jc];
        bfv[jc] = f2bf_rne(f[jc]);
        colw[jc][j8 >> 1] |= bfv[jc] << (16 * (j8 & 1));
      }
      uint4 o;
      o.x = bfv[0] | (bfv[1] << 16); o.y = bfv[2] | (bfv[3] << 16);
      o.z = bfv[4] | (bfv[5] << 16); o.w = bfv[6] | (bfv[7] << 16);
      *(uint4*)(x1 + (tb + (size_t)(rb * 8 + j8)) * H + cg) = o;
    }
    #pragma unroll
    for (int jc = 0; jc < 8; ++jc) {
      const int pos = (cmb + jc + 2 * th) & 15;
      uint4 cw;
      cw.x = colw[jc][0]; cw.y = colw[jc][1]; cw.z = colw[jc][2]; cw.w = colw[jc][3];
      *(uint4*)&frag[bsel][ldsbase + pos * 8] = cw;
    }
  };

  // prologue: tile 0 -> buf 0
  {
    const size_t tb = (size_t)blockIdx.x * 128;
    #pragma unroll
    for (int j8 = 0; j8 < 8; ++j8)
      rv[j8] = *(const uint4*)(x1 + (tb + (size_t)(rb * 8 + j8)) * H + cg);
    PROCESS(0, tb);
  }

  for (int k = 0; k < 16; ++k) {
    __syncthreads();
    const int cur = k & 1;
    const bool hasnext = (k + 1 < 16);
    const size_t tbn = (size_t)(blockIdx.x + (k + 1) * 512) * 128;
    if (hasnext) {
      #pragma unroll
      for (int j8 = 0; j8 < 8; ++j8)
        rv[j8] = *(const uint4*)(x1 + (tbn + (size_t)(rb * 8 + j8)) * H + cg);
    }
    // MFMA on current buffer (hides next tile's global-load latency)
    #pragma unroll
    for (int kk = 0; kk < 4; ++kk) {
      short8 fa[4], fb[4];
      #pragma unroll
      for (int a = 0; a < 4; ++a) {
        const int T = tib + a;
        fa[a] = *(const short8*)&frag[cur][kk * 4096 + T * 512 + lq * 128 + ((cm + 2 * T) & 15) * 8];
      }
      #pragma unroll
      for (int b = 0; b < 4; ++b) {
        const int T = tjb + b;
        fb[b] = *(const short8*)&frag[cur][kk * 4096 + T * 512 + lq * 128 + ((cm + 2 * T) & 15) * 8];
      }
      #pragma unroll
      for (int a = 0; a < 4; ++a)
        #pragma unroll
        for (int b = 0; b < 4; ++b)
          acc[a][b] = __builtin_amdgcn_mfma_f32_16x16x32_bf16(fa[a], fb[b], acc[a][b], 0, 0, 0);
    }
    if (hasnext) PROCESS(cur ^ 1, tbn);
  }

  // colsum: reduce over the 4 row-block groups sharing this thread's 8 columns
  #pragma unroll
  for (int jc = 0; jc < 8; ++jc) {
    cs8[jc] += __shfl_xor(cs8[jc], 16);
    cs8[jc] += __shfl_xor(cs8[jc], 32);
  }
  __syncthreads();                       // frag no longer needed: reuse as fp32 scratch
  float* redp = (float*)&frag[0][0];
  if ((tid & 63) < 16) {
    #pragma unroll
    for (int jc = 0; jc < 8; ++jc) redp[w * 128 + (tid & 15) * 8 + jc] = cs8[jc];
  }
  __syncthreads();
  if (tid < 128)
    atomicAdd(&asum[tid], redp[tid] + redp[128 + tid] + redp[256 + tid] + redp[384 + tid]);

  // G: C/D layout col=lane&15, row=(lane>>4)*4+reg
  #pragma unroll
  for (int a = 0; a < 4; ++a)
    #pragma unroll
    for (int b = 0; b < 4; ++b)
      #pragma unroll
      for (int r = 0; r < 4; ++r)
        atomicAdd(&G[((tib + a) * 16 + lq * 4 + r) * 128 + (tjb + b) * 16 + cm], acc[a][b][r]);
}

// BN2 stats WITHOUT materializing x2: var_j = w2col^T (G/E) w2col - (mu.w2col)^2
extern "C" __global__ __launch_bounds__(256) void k_bn2fin(
    const float* __restrict__ asum, const float* __restrict__ Gm,
    const float* __restrict__ w2, const float* __restrict__ g2,
    const float* __restrict__ be2, float* __restrict__ sc2, float* __restrict__ sh2)
{
  __shared__ float Gs[128 * 128];
  __shared__ float w2s[128 * 128];
  __shared__ float mus[128];
  __shared__ float red[512];
  const int tid = threadIdx.x;
  const int jbase = blockIdx.x * 128;
  for (int i = tid; i < 128 * 128; i += 256) {
    Gs[i] = Gm[i];
    w2s[i] = w2[(i >> 7) * H2 + jbase + (i & 127)];
  }
  if (tid < 128) mus[tid] = asum[tid] * (1.f / (float)E_N);
  __syncthreads();
  const int jj = tid & 127, ih = tid >> 7;
  float m1 = 0.f, q = 0.f;
  for (int i = ih * 64; i < ih * 64 + 64; ++i) {
    const float wi = w2s[i * 128 + jj];
    m1 += mus[i] * wi;
    float si = 0.f;
    #pragma unroll 4
    for (int k = 0; k < 128; ++k) si += Gs[i * 128 + k] * w2s[k * 128 + jj];
    q += wi * si;
  }
  red[tid] = m1; red[256 + tid] = q;
  __syncthreads();
  if (ih == 0) {
    const float m1t = red[jj] + red[jj + 128];
    const float qt  = red[256 + jj] + red[256 + jj + 128];
    const float var = qt * (1.f / (float)E_N) - m1t * m1t;
    const float s = g2[jbase + jj] * rsqrtf(var + EPSf);
    sc2[jbase + jj] = s;
    sh2[jbase + jj] = be2[jbase + jj] - m1t * s;
  }
}

// ---------------- Edge sort by destination: histogram / scan / scatter ----------------
extern "C" __global__ __launch_bounds__(256) void k_hist(
    const int* __restrict__ nbr, int* __restrict__ cnt)
{
  const int e = blockIdx.x * 256 + threadIdx.x;
  atomicAdd(&cnt[nbr[e]], 1);
}

extern "C" __global__ __launch_bounds__(256) void k_scan1(
    const int* __restrict__ cnt, int* __restrict__ bsum)
{
  __shared__ int rs[256];
  const int tid = threadIdx.x, b = blockIdx.x;
  const int4 c = *(const int4*)&cnt[b * 1024 + tid * 4];
  rs[tid] = c.x + c.y + c.z + c.w;
  __syncthreads();
  for (int o = 128; o > 0; o >>= 1) {
    if (tid < o) rs[tid] += rs[tid + o];
    __syncthreads();
  }
  if (tid == 0) bsum[b] = rs[0];
}

extern "C" __global__ void k_scan2(const int* __restrict__ bsum, int* __restrict__ bpre)
{
  __shared__ int bs[128];
  const int tid = threadIdx.x;
  bs[tid] = bsum[tid];
  __syncthreads();
  int p = 0;
  for (int i = 0; i < tid; ++i) p += bs[i];
  bpre[tid] = p;
}

extern "C" __global__ __launch_bounds__(256) void k_scan3(
    const int* __restrict__ cnt, const int* __restrict__ bpre,
    int* __restrict__ cursor, int* __restrict__ rowptr)
{
  __shared__ int tsum[256];
  const int tid = threadIdx.x, b = blockIdx.x;
  const int4 c = *(const int4*)&cnt[b * 1024 + tid * 4];
  const int t1 = c.x, t2 = c.x + c.y, t3 = c.x + c.y + c.z, tot = t3 + c.w;
  tsum[tid] = tot;
  __syncthreads();
  for (int o = 1; o < 256; o <<= 1) {
    const int add = (tid >= o) ? tsum[tid - o] : 0;
    __syncthreads();
    tsum[tid] += add;
    __syncthreads();
  }
  const int excl = (tid == 0) ? 0 : tsum[tid - 1];
  const int base = bpre[b] + excl;
  int4 o4;
  o4.x = base; o4.y = base + t1; o4.z = base + t2; o4.w = base + t3;
  *(int4*)&cursor[b * 1024 + tid * 4] = o4;
  *(int4*)&rowptr[b * 1024 + tid * 4] = o4;
}

extern "C" __global__ __launch_bounds__(256) void k_scatteridx(
    const int* __restrict__ nbr, int* __restrict__ cursor,
    int* __restrict__ sorted_eid)
{
  const int e = blockIdx.x * 256 + threadIdx.x;
  const int v = nbr[e];
  const int pos = atomicAdd(&cursor[v], 1);
  sorted_eid[pos] = e;
}

// pack w2 (fp32 128x256 row-major) into bf16 B-fragment order:
// frag idx i = ((t*4+s)*64 + L)*8 + j  holds  B[k = s*32+(L>>4)*8+j][n = t*16+(L&15)]
extern "C" __global__ void k_packB(const float* __restrict__ w2, __hip_bfloat16* __restrict__ Bpack)
{
  const int i = blockIdx.x * 256 + threadIdx.x;  // 0..32767
  const int j = i & 7, L = (i >> 3) & 63, s = (i >> 9) & 3, t = i >> 11;
  const int k = s * 32 + (L >> 4) * 8 + j;
  const int n = t * 16 + (L & 15);
  Bpack[i] = __float2bfloat16(w2[k * H2 + n]);
}

// ---------------- MFMA msg kernel: 128 sorted edges/block -> msg rows (bf16) ----------------
extern "C" __global__ __launch_bounds__(256) void k_msg(
    const __hip_bfloat16* __restrict__ a1, const int* __restrict__ sorted_eid,
    const __hip_bfloat16* __restrict__ Bpack,
    const float* __restrict__ sc2, const float* __restrict__ sh2,
    __hip_bfloat16* __restrict__ msgbuf, const int eoff)
{
  __shared__ __hip_bfloat16 As[128 * 136];   // a1 tile; reused for msg repack
  __shared__ int eidsh[128];
  __shared__ float sc2s[256], sh2s[256];
  const int tid = threadIdx.x;
  const int s0 = blockIdx.x * 128;           // row base within this half
  if (tid < 128) eidsh[tid] = sorted_eid[eoff + s0 + tid];
  sc2s[tid] = sc2[tid]; sh2s[tid] = sh2[tid];
  __syncthreads();
  // gather a1 rows (pre-activated bf16): 16 uint4 per row
  for (int i = tid; i < 128 * 16; i += 256) {
    const int r = i >> 4, cc = (i & 15) * 8;
    *(uint4*)&As[r * 136 + cc] = *(const uint4*)(a1 + (size_t)eidsh[r] * H + cc);
  }
  __syncthreads();
  const int w = tid >> 6, L = tid & 63, lm = L & 15, q = L >> 4;
  const int m0 = w * 32, m1 = w * 32 + 16;
  f32x4 acc0[16], acc1[16];
  #pragma unroll
  for (int t = 0; t < 16; ++t) { acc0[t] = (f32x4){0.f,0.f,0.f,0.f}; acc1[t] = (f32x4){0.f,0.f,0.f,0.f}; }
  const short8* bp = (const short8*)Bpack;
  #pragma unroll
  for (int s = 0; s < 4; ++s) {
    const short8 af0 = *(const short8*)&As[(m0 + lm) * 136 + s * 32 + q * 8];
    const short8 af1 = *(const short8*)&As[(m1 + lm) * 136 + s * 32 + q * 8];
    #pragma unroll
    for (int t = 0; t < 16; ++t) {
      const short8 bf = bp[(t * 4 + s) * 64 + L];
      acc0[t] = __builtin_amdgcn_mfma_f32_16x16x32_bf16(af0, bf, acc0[t], 0, 0, 0);
      acc1[t] = __builtin_amdgcn_mfma_f32_16x16x32_bf16(af1, bf, acc1[t], 0, 0, 0);
    }
  }
  // epilogue: rows [w*32, w*32+32) belong exclusively to this wave -> safe to overwrite As
  #pragma unroll
  for (int t = 0; t < 8; ++t) {
    const int cF = t * 16 + lm;
    const float scF = sc2s[cF], shF = sh2s[cF];
    const float scC = sc2s[128 + cF], shC = sh2s[128 + cF];
    #pragma unroll
    for (int r = 0; r < 4; ++r) {
      const int row0 = m0 + q * 4 + r, row1 = m1 + q * 4 + r;
      const float f0 = acc0[t][r] * scF + shF;
      const float g0 = acc0[t + 8][r] * scC + shC;
      const float f1 = acc1[t][r] * scF + shF;
      const float g1 = acc1[t + 8][r] * scC + shC;
      ((unsigned short*)As)[row0 * 136 + cF] = (unsigned short)f2bf_rne(sigmf_(f0) * splusf_(g0));
      ((unsigned short*)As)[row1 * 136 + cF] = (unsigned short)f2bf_rne(sigmf_(f1) * splusf_(g1));
    }
  }
  __syncthreads();
  // coalesced store of msg rows
  for (int i = tid; i < 128 * 16; i += 256) {
    const int r = i >> 4, cc = (i & 15) * 8;
    *(uint4*)(msgbuf + ((size_t)(s0 + r)) * H + cc) = *(const uint4*)&As[r * 136 + cc];
  }
}

// ---------------- Segment sum over sorted msg rows: NO atomics, each node owned by one group ----------------
extern "C" __global__ __launch_bounds__(256) void k_segsum(
    const __hip_bfloat16* __restrict__ msgbuf, const int* __restrict__ rowptr,
    const int* __restrict__ cnt, float* __restrict__ h,
    const int w0, const int w1, const int mode)
{
  __shared__ float redA[256], redB[256];
  const int tid = threadIdx.x;
  const int c2 = (tid & 63) * 2;   // column pair
  const int j  = tid >> 6;         // 4-way row split
  const int n0 = blockIdx.x * 16;
  for (int g = 0; g < 16; ++g) {
    const int n = n0 + g;
    const int s = rowptr[n], e = s + cnt[n];
    const int lo = max(s, w0), hi = min(e, w1);
    float s0 = 0.f, s1 = 0.f;
    for (int r = lo + j; r < hi; r += 4) {
      const unsigned int pk = *(const unsigned int*)(msgbuf + ((size_t)(r - w0)) * H + c2);
      s0 += bf2f(pk & 0xffff);
      s1 += bf2f(pk >> 16);
    }
    redA[tid] = s0; redB[tid] = s1;
    __syncthreads();
    if (j == 0) {
      const int t = tid;  // 0..63
      const float t0 = redA[t] + redA[t + 64] + redA[t + 128] + redA[t + 192];
      const float t1 = redB[t] + redB[t + 64] + redB[t + 128] + redB[t + 192];
      float* hp = h + (size_t)n * H + c2;
      if (mode == 0) { hp[0] = t0; hp[1] = t1; }
      else           { hp[0] += t0; hp[1] += t1; }
    }
    __syncthreads();
  }
}

// ---------------- Spectral: CS[b,k,h] = exp(-ev[b,k]*time[h]) * sum_v evinv[b,k,v] h[b,v,h] ----------------
extern "C" __global__ __launch_bounds__(256) void k_spec(
    const float* __restrict__ eigs, const float* __restrict__ h,
    const float* __restrict__ prop_time, int l, float* __restrict__ CS)
{
  __shared__ float Ash[64 * 32];
  __shared__ float Hsh[64 * 128];
  const int tid = threadIdx.x;
  const int b = blockIdx.x >> 2;
  const int kbase = (blockIdx.x & 3) * 32;
  const int k0 = (tid >> 5) * 4;
  const int c0 = (tid & 31) * 4;
  const size_t ebase = (size_t)b * (4097 * 128);
  float acc[4][4] = {};
  for (int vb = 0; vb < V_N; vb += 64) {
    __syncthreads();
    for (int i = tid * 4; i < 64 * 32; i += 1024) {
      const int vv = i >> 5, kk = i & 31;
      *(float4*)&Ash[i] = *(const float4*)&eigs[ebase + (size_t)(2049 + vb + vv) * 128 + kbase + kk];
    }
    for (int i = tid * 4; i < 64 * 128; i += 1024)
      *(float4*)&Hsh[i] = *(const float4*)&h[((size_t)b * V_N + vb) * 128 + i];
    __syncthreads();
    for (int vv = 0; vv < 64; ++vv) {
      const float4 av = *(const float4*)&Ash[vv * 32 + k0];
      const float4 hv = *(const float4*)&Hsh[vv * 128 + c0];
      const float aa[4] = {av.x, av.y, av.z, av.w};
      const float hh[4] = {hv.x, hv.y, hv.z, hv.w};
      #pragma unroll
      for (int a = 0; a < 4; ++a)
        #pragma unroll
        for (int j = 0; j < 4; ++j) acc[a][j] += aa[a] * hh[j];
    }
  }
  #pragma unroll
  for (int a = 0; a < 4; ++a) {
    const float ev = eigs[ebase + kbase + k0 + a];
    #pragma unroll
    for (int j = 0; j < 4; ++j) {
      const float tm = fmaxf(prop_time[l * H + c0 + j], 1e-6f);
      CS[((size_t)b * K_N + kbase + k0 + a) * H + c0 + j] = __expf(-ev * tm) * acc[a][j];
    }
  }
}

// h_prop[b,v,h] = sum_k evecs[b,v,k] * CS[b,k,h]
extern "C" __global__ __launch_bounds__(256) void k_hprop(
    const float* __restrict__ eigs, const float* __restrict__ CS,
    float* __restrict__ hprop)
{
  __shared__ float EvT[32 * EVS];
  __shared__ float CSsh[32 * 128];
  const int tid = threadIdx.x;
  const int b = blockIdx.x >> 4;
  const int vbase = (blockIdx.x & 15) * 128;
  const int v0 = (tid >> 4) * 8;
  const int c0 = (tid & 15) * 8;
  const size_t ebase = (size_t)b * (4097 * 128);
  float acc[8][8] = {};
  for (int kb = 0; kb < K_N; kb += 32) {
    __syncthreads();
    for (int i = tid; i < 128 * 32; i += 256) {
      const int vv = i >> 5, kk = i & 31;
      EvT[kk * EVS + vv] = eigs[ebase + (size_t)(1 + vbase + vv) * 128 + kb + kk];
    }
    for (int i = tid * 4; i < 32 * 128; i += 1024)
      *(float4*)&CSsh[i] = *(const float4*)&CS[((size_t)b * K_N + kb) * 128 + i];
    __syncthreads();
    for (int kk = 0; kk < 32; ++kk) {
      const float4 ea = *(const float4*)&EvT[kk * EVS + v0];
      const float4 eb = *(const float4*)&EvT[kk * EVS + v0 + 4];
      const float4 ca = *(const float4*)&CSsh[kk * 128 + c0];
      const float4 cb = *(const float4*)&CSsh[kk * 128 + c0 + 4];
      const float ee[8] = {ea.x, ea.y, ea.z, ea.w, eb.x, eb.y, eb.z, eb.w};
      const float cc[8] = {ca.x, ca.y, ca.z, ca.w, cb.x, cb.y, cb.z, cb.w};
      #pragma unroll
      for (int a = 0; a < 8; ++a)
        #pragma unroll
        for (int j = 0; j < 8; ++j) acc[a][j] += ee[a] * cc[j];
    }
  }
  #pragma unroll
  for (int a = 0; a < 8; ++a) {
    const size_t row = ((size_t)b * V_N + vbase + v0 + a) * H;
    #pragma unroll
    for (int j = 0; j < 8; j += 4) {
      float4 o;
      o.x = acc[a][j]; o.y = acc[a][j+1]; o.z = acc[a][j+2]; o.w = acc[a][j+3];
      *(float4*)&hprop[row + c0 + j] = o;
    }
  }
}

// ---------------- Generic 128-col GEMM with FUSED column stats of the output ----------------
extern "C" __global__ __launch_bounds__(256) void k_gemm(
    const float* __restrict__ A0, const float* __restrict__ A1,
    const float* __restrict__ W, const float* __restrict__ bias,
    const float* __restrict__ preSc, const float* __restrict__ preSh,
    const int preop, const int KcA, float* __restrict__ out,
    float* __restrict__ sum, float* __restrict__ ssq)
{
  __shared__ float AT[32 * EVS];
  __shared__ float Ws[32 * 128];
  __shared__ float cs[128], cq[128];
  const int tid = threadIdx.x;
  const int rbase = blockIdx.x * 128;
  const int r0 = (tid >> 4) * 8;
  const int c0 = (tid & 15) * 8;
  float acc[8][8] = {};
  for (int kb = 0; kb < KcA; kb += 32) {
    const float* Asrc = (kb < 128) ? A0 : A1;
    const int kloc = kb & 127;
    __syncthreads();
    for (int i = tid; i < 128 * 32; i += 256) {
      const int rr = i >> 5, kk = i & 31;
      float v = Asrc[((size_t)rbase + rr) * H + kloc + kk];
      if (preop) {
        v = v * preSc[kloc + kk] + preSh[kloc + kk];
        v = siluf_(v);
      }
      AT[kk * EVS + rr] = v;
    }
    for (int i = tid * 4; i < 32 * 128; i += 1024)
      *(float4*)&Ws[i] = *(const float4*)&W[(size_t)kb * 128 + i];
    __syncthreads();
    for (int kk = 0; kk < 32; ++kk) {
      const float4 aa4 = *(const float4*)&AT[kk * EVS + r0];
      const float4 ab4 = *(const float4*)&AT[kk * EVS + r0 + 4];
      const float4 wa4 = *(const float4*)&Ws[kk * 128 + c0];
      const float4 wb4 = *(const float4*)&Ws[kk * 128 + c0 + 4];
      const float ar[8] = {aa4.x, aa4.y, aa4.z, aa4.w, ab4.x, ab4.y, ab4.z, ab4.w};
      const float wr[8] = {wa4.x, wa4.y, wa4.z, wa4.w, wb4.x, wb4.y, wb4.z, wb4.w};
      #pragma unroll
      for (int a = 0; a < 8; ++a)
        #pragma unroll
        for (int j = 0; j < 8; ++j) acc[a][j] += ar[a] * wr[j];
    }
  }
  if (tid < 128) { cs[tid] = 0.f; cq[tid] = 0.f; }
  __syncthreads();
  float s8[8] = {}, q8[8] = {};
  #pragma unroll
  for (int a = 0; a < 8; ++a) {
    const size_t row = ((size_t)rbase + r0 + a) * H;
    float val[8];
    #pragma unroll
    for (int j = 0; j < 8; ++j) {
      val[j] = acc[a][j] + bias[c0 + j];
      s8[j] += val[j];
      q8[j] += val[j] * val[j];
    }
    #pragma unroll
    for (int j = 0; j < 8; j += 4) {
      float4 o; o.x = val[j]; o.y = val[j+1]; o.z = val[j+2]; o.w = val[j+3];
      *(float4*)&out[row + c0 + j] = o;
    }
  }
  #pragma unroll
  for (int j = 0; j < 8; ++j) {
    atomicAdd(&cs[c0 + j], s8[j]);
    atomicAdd(&cq[c0 + j], q8[j]);
  }
  __syncthreads();
  if (tid < 128) {
    atomicAdd(&sum[tid], cs[tid]);
    atomicAdd(&ssq[tid], cq[tid]);
  }
}

// h += sc*tb + sh (residual with BN applied)
extern "C" __global__ __launch_bounds__(256) void k_hupd(
    float* __restrict__ h, const float* __restrict__ tb,
    const float* __restrict__ sc, const float* __restrict__ sh)
{
  const int i4 = blockIdx.x * 256 + threadIdx.x;
  const size_t base = (size_t)i4 * 4;
  const int c = (int)(base & 127);
  float4 t = *(const float4*)&tb[base];
  float4 hh = *(const float4*)&h[base];
  hh.x += sc[c+0]*t.x + sh[c+0];
  hh.y += sc[c+1]*t.y + sh[c+1];
  hh.z += sc[c+2]*t.z + sh[c+2];
  hh.w += sc[c+3]*t.w + sh[c+3];
  *(float4*)&h[base] = hh;
}

// head: out[b] = mean_v( silu(bn(ta_row)) . wo2 ) + bo2
extern "C" __global__ __launch_bounds__(256) void k_head(
    const float* __restrict__ ta, const float* __restrict__ sc,
    const float* __restrict__ sh, const float* __restrict__ wo2,
    const float* __restrict__ bo2, float* __restrict__ out)
{
  __shared__ float w2s[128], scs[128], shs[128];
  __shared__ float wred[4];
  const int tid = threadIdx.x;
  if (tid < 128) { w2s[tid] = wo2[tid]; scs[tid] = sc[tid]; shs[tid] = sh[tid]; }
  __syncthreads();
  const int b = blockIdx.x;
  const int wave = tid >> 6, lane = tid & 63;
  const int j = lane * 2;
  const float w0 = w2s[j], w1 = w2s[j+1];
  const float s0 = scs[j], s1 = scs[j+1], t0 = shs[j], t1 = shs[j+1];
  float p = 0.f;
  for (int v = wave; v < V_N; v += 4) {
    const float2 xv = *(const float2*)&ta[((size_t)b * V_N + v) * H + j];
    float x0 = xv.x * s0 + t0; x0 = siluf_(x0);
    float x1 = xv.y * s1 + t1; x1 = siluf_(x1);
    p += x0 * w0 + x1 * w1;
  }
  #pragma unroll
  for (int off = 32; off > 0; off >>= 1) p += __shfl_down(p, off);
  if (lane == 0) wred[wave] = p;
  __syncthreads();
  if (tid == 0) out[b] = (wred[0] + wred[1] + wred[2] + wred[3]) * (1.f / V_N) + bo2[0];
}

extern "C" void kernel_launch(void* const* d_in, const int* in_sizes, int n_in,
                              void* d_out, int out_size, void* d_ws, size_t ws_size,
                              hipStream_t stream) {
  (void)in_sizes; (void)n_in; (void)out_size;
  const float* chem = (const float*)d_in[0];
  const int*   nbr  = (const int*)d_in[1];
  const float* eigs = (const float*)d_in[2];
  const float* w1   = (const float*)d_in[3];
  const float* b1   = (const float*)d_in[4];
  const float* g1   = (const float*)d_in[5];
  const float* be1  = (const float*)d_in[6];
  const float* w2   = (const float*)d_in[7];
  const float* b2   = (const float*)d_in[8];  (void)b2;  // cancels through BN mean
  const float* g2   = (const float*)d_in[9];
  const float* be2  = (const float*)d_in[10];
  const float* prop_time = (const float*)d_in[11];
  const float* pw1  = (const float*)d_in[12];
  const float* pb1  = (const float*)d_in[13];
  const float* pg1  = (const float*)d_in[14];
  const float* pbe1 = (const float*)d_in[15];
  const float* pw2  = (const float*)d_in[16];
  const float* pb2  = (const float*)d_in[17];
  const float* pg2  = (const float*)d_in[18];
  const float* pbe2 = (const float*)d_in[19];
  const float* wo1  = (const float*)d_in[20];
  const float* bo1  = (const float*)d_in[21];
  const float* go1  = (const float*)d_in[22];
  const float* beo1 = (const float*)d_in[23];
  const float* wo2  = (const float*)d_in[24];
  const float* bo2  = (const float*)d_in[25];

  float* ws = (float*)d_ws;
  float* h     = ws;                                   // N*H
  float* hprop = h + (size_t)N_N * H;                  // N*H (pre-loop: msg half-buffer lo)
  float* ta    = hprop + (size_t)N_N * H;              // N*H (pre-loop: msg half-buffer hi)
  float* CS    = ta + (size_t)N_N * H;                 // B*K*H
  float* acc   = CS + (size_t)B_N * K_N * H;           // small accumulators
  float* sum1 = acc,        *ssq1 = acc + 128;
  float* sc1  = acc + 256,  *sh1  = acc + 384;
  float* asum = acc + 512;
  float* G    = acc + 640;                             // 128*128
  float* sc2  = acc + 17024, *sh2 = acc + 17280;
  float* statS = acc + 17536;                          // 7 slots x 256
  float* scA = acc + 19456, *shA = acc + 19584;
  float* scB = acc + 19712, *shB = acc + 19840;
  __hip_bfloat16* x1 = (__hip_bfloat16*)(acc + 19968); // E*H bf16 (becomes a1 after k_a1_gram)

  char* p = (char*)x1 + (size_t)E_N * H * 2;
  int* cnt        = (int*)p;  p += (size_t)N_N * 4;
  int* cursor     = (int*)p;  p += (size_t)N_N * 4;
  int* rowptr     = (int*)p;  p += (size_t)N_N * 4;
  int* bsum       = (int*)p;  p += 512;
  int* bpre       = (int*)p;  p += 512;
  int* sorted_eid = (int*)p;  p += (size_t)E_N * 4;
  __hip_bfloat16* Bpack = (__hip_bfloat16*)p;  p += 65536;

  const size_t req = (size_t)(p - (char*)d_ws);
  if (ws_size < req) return;  // diagnostic: output stays zero -> absmax == 6.396e-2

  // msg half-buffer aliases [hprop, ta] (exactly E/2*H bf16 = 2*N*H fp32 bytes)
  __hip_bfloat16* msgbuf = (__hip_bfloat16*)hprop;

  hipMemsetAsync(acc, 0, 19456 * sizeof(float), stream);
  hipMemsetAsync(cnt, 0, (size_t)N_N * sizeof(int), stream);

  // edge MLP front half + BN params
  k_gemm1_stats<<<E_N / 128, 256, 0, stream>>>(chem, w1, b1, x1, sum1, ssq1);
  k_bnfin<<<1, 128, 0, stream>>>(sum1, ssq1, g1, be1, 1.f / (float)E_N, sc1, sh1);
  k_a1_gram<<<512, 256, 0, stream>>>(x1, sc1, sh1, asum, G);   // also writes a1 in-place
  k_bn2fin<<<2, 256, 0, stream>>>(asum, G, w2, g2, be2, sc2, sh2);

  // sort edges by destination + pack B
  k_packB<<<128, 256, 0, stream>>>(w2, Bpack);
  k_hist<<<E_N / 256, 256, 0, stream>>>(nbr, cnt);
  k_scan1<<<128, 256, 0, stream>>>(cnt, bsum);
  k_scan2<<<1, 128, 0, stream>>>(bsum, bpre);
  k_scan3<<<128, 256, 0, stream>>>(cnt, bpre, cursor, rowptr);
  k_scatteridx<<<E_N / 256, 256, 0, stream>>>(nbr, cursor, sorted_eid);

  // msg (MFMA) + segment-sum, two halves to fit msg in the dead hprop/ta region
  for (int half = 0; half < 2; ++half) {
    const int w0 = half * (E_N / 2), w1e = w0 + E_N / 2;
    k_msg<<<(E_N / 2) / 128, 256, 0, stream>>>(x1, sorted_eid, Bpack, sc2, sh2, msgbuf, w0);
    k_segsum<<<N_N / 16, 256, 0, stream>>>(msgbuf, rowptr, cnt, h, w0, w1e, half);
  }

  float* tb = hprop;
  for (int l = 0; l < 3; ++l) {
    k_spec<<<B_N * 4, 256, 0, stream>>>(eigs, h, prop_time, l, CS);
    k_hprop<<<B_N * 16, 256, 0, stream>>>(eigs, CS, hprop);
    k_gemm<<<N_N / 128, 256, 0, stream>>>(h, hprop, pw1 + (size_t)l * H2 * H, pb1 + l * H,
                                          nullptr, nullptr, 0, H2, ta,
                                          statS + (2 * l) * 256, statS + (2 * l) * 256 + 128);
    k_bnfin<<<1, 128, 0, stream>>>(statS + (2 * l) * 256, statS + (2 * l) * 256 + 128,
                                   pg1 + l * H, pbe1 + l * H, 1.f / (float)N_N, scA, shA);
    k_gemm<<<N_N / 128, 256, 0, stream>>>(ta, nullptr, pw2 + (size_t)l * H * H, pb2 + l * H,
                                          scA, shA, 1, H, tb,
                                          statS + (2 * l + 1) * 256, statS + (2 * l + 1) * 256 + 128);
    k_bnfin<<<1, 128, 0, stream>>>(statS + (2 * l + 1) * 256, statS + (2 * l + 1) * 256 + 128,
                                   pg2 + l * H, pbe2 + l * H, 1.f / (float)N_N, scB, shB);
    k_hupd<<<N_N * H / 1024, 256, 0, stream>>>(h, tb, scB, shB);
  }

  k_gemm<<<N_N / 128, 256, 0, stream>>>(h, nullptr, wo1, bo1, nullptr, nullptr, 0, H, ta,
                                        statS + 6 * 256, statS + 6 * 256 + 128);
  k_bnfin<<<1, 128, 0, stream>>>(statS + 6 * 256, statS + 6 * 256 + 128,
                                 go1, beo1, 1.f / (float)N_N, scA, shA);
  k_head<<<B_N, 256, 0, stream>>>(ta, scA, shA, wo2, bo2, (float*)d_out);
}

// Round 4
// 3258.146 us; speedup vs baseline: 1.2539x; 1.2539x over previous
//
#include <hip/hip_runtime.h>
#include <hip/hip_bf16.h>
#include <math.h>

#define E_N 1048576
#define CF 47
#define H 128
#define H2 256
#define B_N 64
#define V_N 2048
#define K_N 128
#define N_N 131072
#define EPSf 1e-5f
#define EVS 132   // padded LDS leading dim for fp32 tiles

typedef __attribute__((ext_vector_type(8))) short short8;
typedef __attribute__((ext_vector_type(4))) float f32x4;

__device__ __forceinline__ float bf2f(unsigned int u16) {
  union { float f; unsigned int i; } x; x.i = u16 << 16; return x.f;
}
__device__ __forceinline__ unsigned int f2bf_rne(float f) {
  unsigned int u = __float_as_uint(f);
  return (u + 0x7fffu + ((u >> 16) & 1u)) >> 16;
}
__device__ __forceinline__ unsigned int packbf2(float lo, float hi) {
  return f2bf_rne(lo) | (f2bf_rne(hi) << 16);
}
__device__ __forceinline__ float frcp_(float x) { return __builtin_amdgcn_rcpf(x); }
__device__ __forceinline__ float sigmf_(float x) { return frcp_(1.f + __expf(-x)); }
__device__ __forceinline__ float siluf_(float x) { return x * sigmf_(x); }
__device__ __forceinline__ float splusf_(float x) {
  return (x > 15.f) ? x : __logf(1.f + __expf(x));
}

// pack w1 (fp32 CFx128) into bf16 B-fragment order, K padded 47->64 (zeros):
// frag idx i = ((t*2+s)*64 + L)*8 + j  holds  B[k = s*32+(L>>4)*8+j][n = t*16+(L&15)]
extern "C" __global__ void k_packB1(const float* __restrict__ w1, __hip_bfloat16* __restrict__ B1)
{
  const int i = blockIdx.x * 256 + threadIdx.x;  // 0..8191
  const int j = i & 7, L = (i >> 3) & 63, s = (i >> 9) & 1, t = i >> 10;
  const int k = s * 32 + ((L >> 4) * 8) + j;
  const int n = t * 16 + (L & 15);
  B1[i] = __float2bfloat16((k < CF) ? w1[k * H + n] : 0.f);
}

// ---------------- Stage 1: x1 = chem @ w1 + b1 (E x 128) via bf16 MFMA, fused column stats ----
// Per block (128 rows): coalesced float4 stage of the 128x47 fp32 chem tile into LDS,
// per-lane A-fragment build (scalar LDS reads + bf16 pack in regs), 32x mfma_16x16x32_bf16
// against the L2-resident packed B1, then bias+stats in fp32 and LDS-repack -> uint4 store.
// A-stage (24KB fp32) and epilogue repack (34.8KB bf16) share one LDS buffer.
extern "C" __global__ __launch_bounds__(256) void k_gemm1_stats(
    const float* __restrict__ chem, const __hip_bfloat16* __restrict__ B1,
    const float* __restrict__ b1, __hip_bfloat16* __restrict__ x1,
    float* __restrict__ sum1, float* __restrict__ ssq1)
{
  __shared__ __align__(16) unsigned short As[128 * 136];
  __shared__ float bsh[128], cs[128], cq[128];
  float* Afp = (float*)As;
  const int tid = threadIdx.x;
  const int w = tid >> 6, L = tid & 63, lm = L & 15, q = L >> 4;
  const int m0 = w * 32;
  const size_t rowbase = (size_t)blockIdx.x * 128;
  if (tid < 128) { bsh[tid] = b1[tid]; cs[tid] = 0.f; cq[tid] = 0.f; }
  for (int i = tid * 4; i < 128 * CF; i += 1024)
    *(float4*)&Afp[i] = *(const float4*)&chem[rowbase * CF + i];
  __syncthreads();

  // A fragments: lane holds A[m0+mi*16+lm][s*32+q*8+j], j=0..7 (zero-padded k>=47)
  short8 fa[2][2];
  #pragma unroll
  for (int mi = 0; mi < 2; ++mi) {
    const int row = m0 + mi * 16 + lm;
    #pragma unroll
    for (int s = 0; s < 2; ++s) {
      union { unsigned int u[4]; short8 s8; } cvt;
      #pragma unroll
      for (int jp = 0; jp < 4; ++jp) {
        const int k0i = s * 32 + q * 8 + jp * 2;
        const float lo = (k0i     < CF) ? Afp[row * CF + k0i]     : 0.f;
        const float hi = (k0i + 1 < CF) ? Afp[row * CF + k0i + 1] : 0.f;
        cvt.u[jp] = packbf2(lo, hi);
      }
      fa[mi][s] = cvt.s8;
    }
  }
  __syncthreads();   // all frag reads complete before As is reused by the epilogue

  f32x4 acc[2][8];
  #pragma unroll
  for (int mi = 0; mi < 2; ++mi)
    #pragma unroll
    for (int t = 0; t < 8; ++t) acc[mi][t] = (f32x4){0.f, 0.f, 0.f, 0.f};
  const short8* bp = (const short8*)B1;
  #pragma unroll
  for (int s = 0; s < 2; ++s)
    #pragma unroll
    for (int t = 0; t < 8; ++t) {
      const short8 bf = bp[(t * 2 + s) * 64 + L];
      acc[0][t] = __builtin_amdgcn_mfma_f32_16x16x32_bf16(fa[0][s], bf, acc[0][t], 0, 0, 0);
      acc[1][t] = __builtin_amdgcn_mfma_f32_16x16x32_bf16(fa[1][s], bf, acc[1][t], 0, 0, 0);
    }

  // epilogue: bias + stats (fp32, pre-rounding) + bf16 repack into As (own rows only)
  float cs8[8], cq8[8];
  #pragma unroll
  for (int t = 0; t < 8; ++t) { cs8[t] = 0.f; cq8[t] = 0.f; }
  #pragma unroll
  for (int t = 0; t < 8; ++t) {
    const int c = t * 16 + lm;
    const float bb = bsh[c];
    #pragma unroll
    for (int mi = 0; mi < 2; ++mi)
      #pragma unroll
      for (int r = 0; r < 4; ++r) {
        const float v = acc[mi][t][r] + bb;
        cs8[t] += v; cq8[t] += v * v;
        As[(m0 + mi * 16 + q * 4 + r) * 136 + c] = (unsigned short)f2bf_rne(v);
      }
  }
  #pragma unroll
  for (int t = 0; t < 8; ++t) {
    cs8[t] += __shfl_xor(cs8[t], 16); cs8[t] += __shfl_xor(cs8[t], 32);
    cq8[t] += __shfl_xor(cq8[t], 16); cq8[t] += __shfl_xor(cq8[t], 32);
  }
  if (q == 0) {
    #pragma unroll
    for (int t = 0; t < 8; ++t) {
      atomicAdd(&cs[t * 16 + lm], cs8[t]);
      atomicAdd(&cq[t * 16 + lm], cq8[t]);
    }
  }
  __syncthreads();
  for (int i = tid; i < 128 * 16; i += 256) {
    const int r = i >> 4, cc = (i & 15) * 8;
    *(uint4*)(x1 + (rowbase + r) * H + cc) = *(const uint4*)&As[r * 136 + cc];
  }
  if (tid < 128) {
    atomicAdd(&sum1[tid], cs[tid]);
    atomicAdd(&ssq1[tid], cq[tid]);
  }
}

// BN finalize: scale/shift from sum/sumsq (biased var, matches jnp.var)
extern "C" __global__ void k_bnfin(const float* __restrict__ sum, const float* __restrict__ ssq,
    const float* __restrict__ g, const float* __restrict__ be, float invn,
    float* __restrict__ sc, float* __restrict__ sh)
{
  const int c = threadIdx.x;
  const float m = sum[c] * invn;
  const float v = ssq[c] * invn - m * m;
  const float s = g[c] * rsqrtf(v + EPSf);
  sc[c] = s;
  sh[c] = be[c] - m * s;
}

// ---------------- a1 = silu(bn1(x1)); Gram G = a1^T a1 via MFMA; writes a1 (bf16) back IN-PLACE ----
// Per tile (128 rows): each thread stages an 8x8 block (global uint4 reads, in-register
// 8x8 bf16 transpose), writes MFMA-fragment-layout LDS (b128, bank-rotated by pos=(cm+2t)&15).
// frag elem idx = kb*4096 + t*512 + q*128 + pos*8 + j8  holds a1[kb*32+q*8+j8][t*16+cm].
// A- and B-operand layouts of 16x16x32 coincide, so frag(t) serves both sides of G = a^T a.
extern "C" __global__ __launch_bounds__(256) void k_a1_gram(
    __hip_bfloat16* __restrict__ x1, const float* __restrict__ sc1,
    const float* __restrict__ sh1, float* __restrict__ asum, float* __restrict__ G)
{
  __shared__ __align__(16) unsigned short frag[2][16384];   // 2 x 32 KB, double-buffered
  const int tid = threadIdx.x;
  // stage-side ids: thread owns rows [rb*8, rb*8+8) x cols [u*8, u*8+8)
  const int rb = tid >> 4, u = tid & 15;
  const int kb = rb >> 2, qw = rb & 3;
  const int th = u >> 1;                 // subtile column group 0..7
  const int cmb = (u & 1) * 8;
  const int cg = u * 8;
  // MFMA-side ids
  const int w = tid >> 6;
  const int lq = (tid >> 4) & 3;         // lane>>4 within wave
  const int cm = tid & 15;               // lane&15
  const int tib = (w >> 1) * 4, tjb = (w & 1) * 4;   // wave's 4x4 block of 16x16 G-tiles

  float scv[8], shv[8];
  #pragma unroll
  for (int jc = 0; jc < 8; ++jc) { scv[jc] = sc1[cg + jc]; shv[jc] = sh1[cg + jc]; }

  float cs8[8] = {0.f, 0.f, 0.f, 0.f, 0.f, 0.f, 0.f, 0.f};
  f32x4 acc[4][4];
  #pragma unroll
  for (int a = 0; a < 4; ++a)
    #pragma unroll
    for (int b = 0; b < 4; ++b) acc[a][b] = (f32x4){0.f, 0.f, 0.f, 0.f};

  const int ldsbase = kb * 4096 + th * 512 + qw * 128;
  uint4 rv[8];

  // silu + colsum + bf16 pack + global write-back + frag-LDS write of the 8x8 block in rv
  auto PROCESS = [&](int bsel, size_t tb) {
    unsigned int colw[8][4];
    #pragma unroll
    for (int jc = 0; jc < 8; ++jc) { colw[jc][0] = 0; colw[jc][1] = 0; colw[jc][2] = 0; colw[jc][3] = 0; }
    #pragma unroll
    for (int j8 = 0; j8 < 8; ++j8) {
      const uint4 pk = rv[j8];
      float f[8];
      f[0] = bf2f(pk.x & 0xffff); f[1] = bf2f(pk.x >> 16);
      f[2] = bf2f(pk.y & 0xffff); f[3] = bf2f(pk.y >> 16);
      f[4] = bf2f(pk.z & 0xffff); f[5] = bf2f(pk.z >> 16);
      f[6] = bf2f(pk.w & 0xffff); f[7] = bf2f(pk.w >> 16);
      unsigned int bfv[8];
      #pragma unroll
      for (int jc = 0; jc < 8; ++jc) {
        f[jc] = siluf_(f[jc] * scv[jc] + shv[jc]);
        cs8[jc] += f[jc];
        bfv[jc] = f2bf_rne(f[jc]);
        colw[jc][j8 >> 1] |= bfv[jc] << (16 * (j8 & 1));
      }
      uint4 o;
      o.x = bfv[0] | (bfv[1] << 16); o.y = bfv[2] | (bfv[3] << 16);
      o.z = bfv[4] | (bfv[5] << 16); o.w = bfv[6] | (bfv[7] << 16);
      *(uint4*)(x1 + (tb + (size_t)(rb * 8 + j8)) * H + cg) = o;
    }
    #pragma unroll
    for (int jc = 0; jc < 8; ++jc) {
      const int pos = (cmb + jc + 2 * th) & 15;
      uint4 cw;
      cw.x = colw[jc][0]; cw.y = colw[jc][1]; cw.z = colw[jc][2]; cw.w = colw[jc][3];
      *(uint4*)&frag[bsel][ldsbase + pos * 8] = cw;
    }
  };

  // prologue: tile 0 -> buf 0
  {
    const size_t tb = (size_t)blockIdx.x * 128;
    #pragma unroll
    for (int j8 = 0; j8 < 8; ++j8)
      rv[j8] = *(const uint4*)(x1 + (tb + (size_t)(rb * 8 + j8)) * H + cg);
    PROCESS(0, tb);
  }

  for (int k = 0; k < 16; ++k) {
    __syncthreads();
    const int cur = k & 1;
    const bool hasnext = (k + 1 < 16);
    const size_t tbn = (size_t)(blockIdx.x + (k + 1) * 512) * 128;
    if (hasnext) {
      #pragma unroll
      for (int j8 = 0; j8 < 8; ++j8)
        rv[j8] = *(const uint4*)(x1 + (tbn + (size_t)(rb * 8 + j8)) * H + cg);
    }
    // MFMA on current buffer (hides next tile's global-load latency)
    #pragma unroll
    for (int kk = 0; kk < 4; ++kk) {
      short8 fa[4], fb[4];
      #pragma unroll
      for (int a = 0; a < 4; ++a) {
        const int T = tib + a;
        fa[a] = *(const short8*)&frag[cur][kk * 4096 + T * 512 + lq * 128 + ((cm + 2 * T) & 15) * 8];
      }
      #pragma unroll
      for (int b = 0; b < 4; ++b) {
        const int T = tjb + b;
        fb[b] = *(const short8*)&frag[cur][kk * 4096 + T * 512 + lq * 128 + ((cm + 2 * T) & 15) * 8];
      }
      #pragma unroll
      for (int a = 0; a < 4; ++a)
        #pragma unroll
        for (int b = 0; b < 4; ++b)
          acc[a][b] = __builtin_amdgcn_mfma_f32_16x16x32_bf16(fa[a], fb[b], acc[a][b], 0, 0, 0);
    }
    if (hasnext) PROCESS(cur ^ 1, tbn);
  }

  // colsum: reduce over the 4 row-block groups sharing this thread's 8 columns
  #pragma unroll
  for (int jc = 0; jc < 8; ++jc) {
    cs8[jc] += __shfl_xor(cs8[jc], 16);
    cs8[jc] += __shfl_xor(cs8[jc], 32);
  }
  __syncthreads();                       // frag no longer needed: reuse as fp32 scratch
  float* redp = (float*)&frag[0][0];
  if ((tid & 63) < 16) {
    #pragma unroll
    for (int jc = 0; jc < 8; ++jc) redp[w * 128 + (tid & 15) * 8 + jc] = cs8[jc];
  }
  __syncthreads();
  if (tid < 128)
    atomicAdd(&asum[tid], redp[tid] + redp[128 + tid] + redp[256 + tid] + redp[384 + tid]);

  // G: C/D layout col=lane&15, row=(lane>>4)*4+reg
  #pragma unroll
  for (int a = 0; a < 4; ++a)
    #pragma unroll
    for (int b = 0; b < 4; ++b)
      #pragma unroll
      for (int r = 0; r < 4; ++r)
        atomicAdd(&G[((tib + a) * 16 + lq * 4 + r) * 128 + (tjb + b) * 16 + cm], acc[a][b][r]);
}

// BN2 stats WITHOUT materializing x2: var_j = w2col^T (G/E) w2col - (mu.w2col)^2
extern "C" __global__ __launch_bounds__(256) void k_bn2fin(
    const float* __restrict__ asum, const float* __restrict__ Gm,
    const float* __restrict__ w2, const float* __restrict__ g2,
    const float* __restrict__ be2, float* __restrict__ sc2, float* __restrict__ sh2)
{
  __shared__ float Gs[128 * 128];
  __shared__ float w2s[128 * 128];
  __shared__ float mus[128];
  __shared__ float red[512];
  const int tid = threadIdx.x;
  const int jbase = blockIdx.x * 128;
  for (int i = tid; i < 128 * 128; i += 256) {
    Gs[i] = Gm[i];
    w2s[i] = w2[(i >> 7) * H2 + jbase + (i & 127)];
  }
  if (tid < 128) mus[tid] = asum[tid] * (1.f / (float)E_N);
  __syncthreads();
  const int jj = tid & 127, ih = tid >> 7;
  float m1 = 0.f, q = 0.f;
  for (int i = ih * 64; i < ih * 64 + 64; ++i) {
    const float wi = w2s[i * 128 + jj];
    m1 += mus[i] * wi;
    float si = 0.f;
    #pragma unroll 4
    for (int k = 0; k < 128; ++k) si += Gs[i * 128 + k] * w2s[k * 128 + jj];
    q += wi * si;
  }
  red[tid] = m1; red[256 + tid] = q;
  __syncthreads();
  if (ih == 0) {
    const float m1t = red[jj] + red[jj + 128];
    const float qt  = red[256 + jj] + red[256 + jj + 128];
    const float var = qt * (1.f / (float)E_N) - m1t * m1t;
    const float s = g2[jbase + jj] * rsqrtf(var + EPSf);
    sc2[jbase + jj] = s;
    sh2[jbase + jj] = be2[jbase + jj] - m1t * s;
  }
}

// ---------------- Edge sort by destination: histogram / scan / scatter ----------------
extern "C" __global__ __launch_bounds__(256) void k_hist(
    const int* __restrict__ nbr, int* __restrict__ cnt)
{
  const int e = blockIdx.x * 256 + threadIdx.x;
  atomicAdd(&cnt[nbr[e]], 1);
}

extern "C" __global__ __launch_bounds__(256) void k_scan1(
    const int* __restrict__ cnt, int* __restrict__ bsum)
{
  __shared__ int rs[256];
  const int tid = threadIdx.x, b = blockIdx.x;
  const int4 c = *(const int4*)&cnt[b * 1024 + tid * 4];
  rs[tid] = c.x + c.y + c.z + c.w;
  __syncthreads();
  for (int o = 128; o > 0; o >>= 1) {
    if (tid < o) rs[tid] += rs[tid + o];
    __syncthreads();
  }
  if (tid == 0) bsum[b] = rs[0];
}

extern "C" __global__ void k_scan2(const int* __restrict__ bsum, int* __restrict__ bpre)
{
  __shared__ int bs[128];
  const int tid = threadIdx.x;
  bs[tid] = bsum[tid];
  __syncthreads();
  int p = 0;
  for (int i = 0; i < tid; ++i) p += bs[i];
  bpre[tid] = p;
}

extern "C" __global__ __launch_bounds__(256) void k_scan3(
    const int* __restrict__ cnt, const int* __restrict__ bpre,
    int* __restrict__ cursor, int* __restrict__ rowptr)
{
  __shared__ int tsum[256];
  const int tid = threadIdx.x, b = blockIdx.x;
  const int4 c = *(const int4*)&cnt[b * 1024 + tid * 4];
  const int t1 = c.x, t2 = c.x + c.y, t3 = c.x + c.y + c.z, tot = t3 + c.w;
  tsum[tid] = tot;
  __syncthreads();
  for (int o = 1; o < 256; o <<= 1) {
    const int add = (tid >= o) ? tsum[tid - o] : 0;
    __syncthreads();
    tsum[tid] += add;
    __syncthreads();
  }
  const int excl = (tid == 0) ? 0 : tsum[tid - 1];
  const int base = bpre[b] + excl;
  int4 o4;
  o4.x = base; o4.y = base + t1; o4.z = base + t2; o4.w = base + t3;
  *(int4*)&cursor[b * 1024 + tid * 4] = o4;
  *(int4*)&rowptr[b * 1024 + tid * 4] = o4;
}

extern "C" __global__ __launch_bounds__(256) void k_scatteridx(
    const int* __restrict__ nbr, int* __restrict__ cursor,
    int* __restrict__ sorted_eid)
{
  const int e = blockIdx.x * 256 + threadIdx.x;
  const int v = nbr[e];
  const int pos = atomicAdd(&cursor[v], 1);
  sorted_eid[pos] = e;
}

// pack w2 (fp32 128x256 row-major) into bf16 B-fragment order:
// frag idx i = ((t*4+s)*64 + L)*8 + j  holds  B[k = s*32+(L>>4)*8+j][n = t*16+(L&15)]
extern "C" __global__ void k_packB(const float* __restrict__ w2, __hip_bfloat16* __restrict__ Bpack)
{
  const int i = blockIdx.x * 256 + threadIdx.x;  // 0..32767
  const int j = i & 7, L = (i >> 3) & 63, s = (i >> 9) & 3, t = i >> 11;
  const int k = s * 32 + (L >> 4) * 8 + j;
  const int n = t * 16 + (L & 15);
  Bpack[i] = __float2bfloat16(w2[k * H2 + n]);
}

// ---------------- MFMA msg kernel: 128 sorted edges/block -> msg rows (bf16) ----------------
extern "C" __global__ __launch_bounds__(256) void k_msg(
    const __hip_bfloat16* __restrict__ a1, const int* __restrict__ sorted_eid,
    const __hip_bfloat16* __restrict__ Bpack,
    const float* __restrict__ sc2, const float* __restrict__ sh2,
    __hip_bfloat16* __restrict__ msgbuf, const int eoff)
{
  __shared__ __hip_bfloat16 As[128 * 136];   // a1 tile; reused for msg repack
  __shared__ int eidsh[128];
  __shared__ float sc2s[256], sh2s[256];
  const int tid = threadIdx.x;
  const int s0 = blockIdx.x * 128;           // row base within this half
  if (tid < 128) eidsh[tid] = sorted_eid[eoff + s0 + tid];
  sc2s[tid] = sc2[tid]; sh2s[tid] = sh2[tid];
  __syncthreads();
  // gather a1 rows (pre-activated bf16): 16 uint4 per row
  for (int i = tid; i < 128 * 16; i += 256) {
    const int r = i >> 4, cc = (i & 15) * 8;
    *(uint4*)&As[r * 136 + cc] = *(const uint4*)(a1 + (size_t)eidsh[r] * H + cc);
  }
  __syncthreads();
  const int w = tid >> 6, L = tid & 63, lm = L & 15, q = L >> 4;
  const int m0 = w * 32, m1 = w * 32 + 16;
  f32x4 acc0[16], acc1[16];
  #pragma unroll
  for (int t = 0; t < 16; ++t) { acc0[t] = (f32x4){0.f,0.f,0.f,0.f}; acc1[t] = (f32x4){0.f,0.f,0.f,0.f}; }
  const short8* bp = (const short8*)Bpack;
  #pragma unroll
  for (int s = 0; s < 4; ++s) {
    const short8 af0 = *(const short8*)&As[(m0 + lm) * 136 + s * 32 + q * 8];
    const short8 af1 = *(const short8*)&As[(m1 + lm) * 136 + s * 32 + q * 8];
    #pragma unroll
    for (int t = 0; t < 16; ++t) {
      const short8 bf = bp[(t * 4 + s) * 64 + L];
      acc0[t] = __builtin_amdgcn_mfma_f32_16x16x32_bf16(af0, bf, acc0[t], 0, 0, 0);
      acc1[t] = __builtin_amdgcn_mfma_f32_16x16x32_bf16(af1, bf, acc1[t], 0, 0, 0);
    }
  }
  // epilogue: rows [w*32, w*32+32) belong exclusively to this wave -> safe to overwrite As
  #pragma unroll
  for (int t = 0; t < 8; ++t) {
    const int cF = t * 16 + lm;
    const float scF = sc2s[cF], shF = sh2s[cF];
    const float scC = sc2s[128 + cF], shC = sh2s[128 + cF];
    #pragma unroll
    for (int r = 0; r < 4; ++r) {
      const int row0 = m0 + q * 4 + r, row1 = m1 + q * 4 + r;
      const float f0 = acc0[t][r] * scF + shF;
      const float g0 = acc0[t + 8][r] * scC + shC;
      const float f1 = acc1[t][r] * scF + shF;
      const float g1 = acc1[t + 8][r] * scC + shC;
      ((unsigned short*)As)[row0 * 136 + cF] = (unsigned short)f2bf_rne(sigmf_(f0) * splusf_(g0));
      ((unsigned short*)As)[row1 * 136 + cF] = (unsigned short)f2bf_rne(sigmf_(f1) * splusf_(g1));
    }
  }
  __syncthreads();
  // coalesced store of msg rows
  for (int i = tid; i < 128 * 16; i += 256) {
    const int r = i >> 4, cc = (i & 15) * 8;
    *(uint4*)(msgbuf + ((size_t)(s0 + r)) * H + cc) = *(const uint4*)&As[r * 136 + cc];
  }
}

// ---------------- Segment sum over sorted msg rows: NO atomics, each node owned by one group ----------------
extern "C" __global__ __launch_bounds__(256) void k_segsum(
    const __hip_bfloat16* __restrict__ msgbuf, const int* __restrict__ rowptr,
    const int* __restrict__ cnt, float* __restrict__ h,
    const int w0, const int w1, const int mode)
{
  __shared__ float redA[256], redB[256];
  const int tid = threadIdx.x;
  const int c2 = (tid & 63) * 2;   // column pair
  const int j  = tid >> 6;         // 4-way row split
  const int n0 = blockIdx.x * 16;
  for (int g = 0; g < 16; ++g) {
    const int n = n0 + g;
    const int s = rowptr[n], e = s + cnt[n];
    const int lo = max(s, w0), hi = min(e, w1);
    float s0 = 0.f, s1 = 0.f;
    for (int r = lo + j; r < hi; r += 4) {
      const unsigned int pk = *(const unsigned int*)(msgbuf + ((size_t)(r - w0)) * H + c2);
      s0 += bf2f(pk & 0xffff);
      s1 += bf2f(pk >> 16);
    }
    redA[tid] = s0; redB[tid] = s1;
    __syncthreads();
    if (j == 0) {
      const int t = tid;  // 0..63
      const float t0 = redA[t] + redA[t + 64] + redA[t + 128] + redA[t + 192];
      const float t1 = redB[t] + redB[t + 64] + redB[t + 128] + redB[t + 192];
      float* hp = h + (size_t)n * H + c2;
      if (mode == 0) { hp[0] = t0; hp[1] = t1; }
      else           { hp[0] += t0; hp[1] += t1; }
    }
    __syncthreads();
  }
}

// ---------------- Spectral: CS[b,k,h] = exp(-ev[b,k]*time[h]) * sum_v evinv[b,k,v] h[b,v,h] ----------------
extern "C" __global__ __launch_bounds__(256) void k_spec(
    const float* __restrict__ eigs, const float* __restrict__ h,
    const float* __restrict__ prop_time, int l, float* __restrict__ CS)
{
  __shared__ float Ash[64 * 32];
  __shared__ float Hsh[64 * 128];
  const int tid = threadIdx.x;
  const int b = blockIdx.x >> 2;
  const int kbase = (blockIdx.x & 3) * 32;
  const int k0 = (tid >> 5) * 4;
  const int c0 = (tid & 31) * 4;
  const size_t ebase = (size_t)b * (4097 * 128);
  float acc[4][4] = {};
  for (int vb = 0; vb < V_N; vb += 64) {
    __syncthreads();
    for (int i = tid * 4; i < 64 * 32; i += 1024) {
      const int vv = i >> 5, kk = i & 31;
      *(float4*)&Ash[i] = *(const float4*)&eigs[ebase + (size_t)(2049 + vb + vv) * 128 + kbase + kk];
    }
    for (int i = tid * 4; i < 64 * 128; i += 1024)
      *(float4*)&Hsh[i] = *(const float4*)&h[((size_t)b * V_N + vb) * 128 + i];
    __syncthreads();
    for (int vv = 0; vv < 64; ++vv) {
      const float4 av = *(const float4*)&Ash[vv * 32 + k0];
      const float4 hv = *(const float4*)&Hsh[vv * 128 + c0];
      const float aa[4] = {av.x, av.y, av.z, av.w};
      const float hh[4] = {hv.x, hv.y, hv.z, hv.w};
      #pragma unroll
      for (int a = 0; a < 4; ++a)
        #pragma unroll
        for (int j = 0; j < 4; ++j) acc[a][j] += aa[a] * hh[j];
    }
  }
  #pragma unroll
  for (int a = 0; a < 4; ++a) {
    const float ev = eigs[ebase + kbase + k0 + a];
    #pragma unroll
    for (int j = 0; j < 4; ++j) {
      const float tm = fmaxf(prop_time[l * H + c0 + j], 1e-6f);
      CS[((size_t)b * K_N + kbase + k0 + a) * H + c0 + j] = __expf(-ev * tm) * acc[a][j];
    }
  }
}

// h_prop[b,v,h] = sum_k evecs[b,v,k] * CS[b,k,h]
extern "C" __global__ __launch_bounds__(256) void k_hprop(
    const float* __restrict__ eigs, const float* __restrict__ CS,
    float* __restrict__ hprop)
{
  __shared__ float EvT[32 * EVS];
  __shared__ float CSsh[32 * 128];
  const int tid = threadIdx.x;
  const int b = blockIdx.x >> 4;
  const int vbase = (blockIdx.x & 15) * 128;
  const int v0 = (tid >> 4) * 8;
  const int c0 = (tid & 15) * 8;
  const size_t ebase = (size_t)b * (4097 * 128);
  float acc[8][8] = {};
  for (int kb = 0; kb < K_N; kb += 32) {
    __syncthreads();
    for (int i = tid; i < 128 * 32; i += 256) {
      const int vv = i >> 5, kk = i & 31;
      EvT[kk * EVS + vv] = eigs[ebase + (size_t)(1 + vbase + vv) * 128 + kb + kk];
    }
    for (int i = tid * 4; i < 32 * 128; i += 1024)
      *(float4*)&CSsh[i] = *(const float4*)&CS[((size_t)b * K_N + kb) * 128 + i];
    __syncthreads();
    for (int kk = 0; kk < 32; ++kk) {
      const float4 ea = *(const float4*)&EvT[kk * EVS + v0];
      const float4 eb = *(const float4*)&EvT[kk * EVS + v0 + 4];
      const float4 ca = *(const float4*)&CSsh[kk * 128 + c0];
      const float4 cb = *(const float4*)&CSsh[kk * 128 + c0 + 4];
      const float ee[8] = {ea.x, ea.y, ea.z, ea.w, eb.x, eb.y, eb.z, eb.w};
      const float cc[8] = {ca.x, ca.y, ca.z, ca.w, cb.x, cb.y, cb.z, cb.w};
      #pragma unroll
      for (int a = 0; a < 8; ++a)
        #pragma unroll
        for (int j = 0; j < 8; ++j) acc[a][j] += ee[a] * cc[j];
    }
  }
  #pragma unroll
  for (int a = 0; a < 8; ++a) {
    const size_t row = ((size_t)b * V_N + vbase + v0 + a) * H;
    #pragma unroll
    for (int j = 0; j < 8; j += 4) {
      float4 o;
      o.x = acc[a][j]; o.y = acc[a][j+1]; o.z = acc[a][j+2]; o.w = acc[a][j+3];
      *(float4*)&hprop[row + c0 + j] = o;
    }
  }
}

// ---------------- Generic 128-col GEMM with FUSED column stats of the output ----------------
extern "C" __global__ __launch_bounds__(256) void k_gemm(
    const float* __restrict__ A0, const float* __restrict__ A1,
    const float* __restrict__ W, const float* __restrict__ bias,
    const float* __restrict__ preSc, const float* __restrict__ preSh,
    const int preop, const int KcA, float* __restrict__ out,
    float* __restrict__ sum, float* __restrict__ ssq)
{
  __shared__ float AT[32 * EVS];
  __shared__ float Ws[32 * 128];
  __shared__ float cs[128], cq[128];
  const int tid = threadIdx.x;
  const int rbase = blockIdx.x * 128;
  const int r0 = (tid >> 4) * 8;
  const int c0 = (tid & 15) * 8;
  float acc[8][8] = {};
  for (int kb = 0; kb < KcA; kb += 32) {
    const float* Asrc = (kb < 128) ? A0 : A1;
    const int kloc = kb & 127;
    __syncthreads();
    for (int i = tid; i < 128 * 32; i += 256) {
      const int rr = i >> 5, kk = i & 31;
      float v = Asrc[((size_t)rbase + rr) * H + kloc + kk];
      if (preop) {
        v = v * preSc[kloc + kk] + preSh[kloc + kk];
        v = siluf_(v);
      }
      AT[kk * EVS + rr] = v;
    }
    for (int i = tid * 4; i < 32 * 128; i += 1024)
      *(float4*)&Ws[i] = *(const float4*)&W[(size_t)kb * 128 + i];
    __syncthreads();
    for (int kk = 0; kk < 32; ++kk) {
      const float4 aa4 = *(const float4*)&AT[kk * EVS + r0];
      const float4 ab4 = *(const float4*)&AT[kk * EVS + r0 + 4];
      const float4 wa4 = *(const float4*)&Ws[kk * 128 + c0];
      const float4 wb4 = *(const float4*)&Ws[kk * 128 + c0 + 4];
      const float ar[8] = {aa4.x, aa4.y, aa4.z, aa4.w, ab4.x, ab4.y, ab4.z, ab4.w};
      const float wr[8] = {wa4.x, wa4.y, wa4.z, wa4.w, wb4.x, wb4.y, wb4.z, wb4.w};
      #pragma unroll
      for (int a = 0; a < 8; ++a)
        #pragma unroll
        for (int j = 0; j < 8; ++j) acc[a][j] += ar[a] * wr[j];
    }
  }
  if (tid < 128) { cs[tid] = 0.f; cq[tid] = 0.f; }
  __syncthreads();
  float s8[8] = {}, q8[8] = {};
  #pragma unroll
  for (int a = 0; a < 8; ++a) {
    const size_t row = ((size_t)rbase + r0 + a) * H;
    float val[8];
    #pragma unroll
    for (int j = 0; j < 8; ++j) {
      val[j] = acc[a][j] + bias[c0 + j];
      s8[j] += val[j];
      q8[j] += val[j] * val[j];
    }
    #pragma unroll
    for (int j = 0; j < 8; j += 4) {
      float4 o; o.x = val[j]; o.y = val[j+1]; o.z = val[j+2]; o.w = val[j+3];
      *(float4*)&out[row + c0 + j] = o;
    }
  }
  #pragma unroll
  for (int j = 0; j < 8; ++j) {
    atomicAdd(&cs[c0 + j], s8[j]);
    atomicAdd(&cq[c0 + j], q8[j]);
  }
  __syncthreads();
  if (tid < 128) {
    atomicAdd(&sum[tid], cs[tid]);
    atomicAdd(&ssq[tid], cq[tid]);
  }
}

// h += sc*tb + sh (residual with BN applied)
extern "C" __global__ __launch_bounds__(256) void k_hupd(
    float* __restrict__ h, const float* __restrict__ tb,
    const float* __restrict__ sc, const float* __restrict__ sh)
{
  const int i4 = blockIdx.x * 256 + threadIdx.x;
  const size_t base = (size_t)i4 * 4;
  const int c = (int)(base & 127);
  float4 t = *(const float4*)&tb[base];
  float4 hh = *(const float4*)&h[base];
  hh.x += sc[c+0]*t.x + sh[c+0];
  hh.y += sc[c+1]*t.y + sh[c+1];
  hh.z += sc[c+2]*t.z + sh[c+2];
  hh.w += sc[c+3]*t.w + sh[c+3];
  *(float4*)&h[base] = hh;
}

// head: out[b] = mean_v( silu(bn(ta_row)) . wo2 ) + bo2
extern "C" __global__ __launch_bounds__(256) void k_head(
    const float* __restrict__ ta, const float* __restrict__ sc,
    const float* __restrict__ sh, const float* __restrict__ wo2,
    const float* __restrict__ bo2, float* __restrict__ out)
{
  __shared__ float w2s[128], scs[128], shs[128];
  __shared__ float wred[4];
  const int tid = threadIdx.x;
  if (tid < 128) { w2s[tid] = wo2[tid]; scs[tid] = sc[tid]; shs[tid] = sh[tid]; }
  __syncthreads();
  const int b = blockIdx.x;
  const int wave = tid >> 6, lane = tid & 63;
  const int j = lane * 2;
  const float w0 = w2s[j], w1 = w2s[j+1];
  const float s0 = scs[j], s1 = scs[j+1], t0 = shs[j], t1 = shs[j+1];
  float p = 0.f;
  for (int v = wave; v < V_N; v += 4) {
    const float2 xv = *(const float2*)&ta[((size_t)b * V_N + v) * H + j];
    float x0 = xv.x * s0 + t0; x0 = siluf_(x0);
    float x1 = xv.y * s1 + t1; x1 = siluf_(x1);
    p += x0 * w0 + x1 * w1;
  }
  #pragma unroll
  for (int off = 32; off > 0; off >>= 1) p += __shfl_down(p, off);
  if (lane == 0) wred[wave] = p;
  __syncthreads();
  if (tid == 0) out[b] = (wred[0] + wred[1] + wred[2] + wred[3]) * (1.f / V_N) + bo2[0];
}

extern "C" void kernel_launch(void* const* d_in, const int* in_sizes, int n_in,
                              void* d_out, int out_size, void* d_ws, size_t ws_size,
                              hipStream_t stream) {
  (void)in_sizes; (void)n_in; (void)out_size;
  const float* chem = (const float*)d_in[0];
  const int*   nbr  = (const int*)d_in[1];
  const float* eigs = (const float*)d_in[2];
  const float* w1   = (const float*)d_in[3];
  const float* b1   = (const float*)d_in[4];
  const float* g1   = (const float*)d_in[5];
  const float* be1  = (const float*)d_in[6];
  const float* w2   = (const float*)d_in[7];
  const float* b2   = (const float*)d_in[8];  (void)b2;  // cancels through BN mean
  const float* g2   = (const float*)d_in[9];
  const float* be2  = (const float*)d_in[10];
  const float* prop_time = (const float*)d_in[11];
  const float* pw1  = (const float*)d_in[12];
  const float* pb1  = (const float*)d_in[13];
  const float* pg1  = (const float*)d_in[14];
  const float* pbe1 = (const float*)d_in[15];
  const float* pw2  = (const float*)d_in[16];
  const float* pb2  = (const float*)d_in[17];
  const float* pg2  = (const float*)d_in[18];
  const float* pbe2 = (const float*)d_in[19];
  const float* wo1  = (const float*)d_in[20];
  const float* bo1  = (const float*)d_in[21];
  const float* go1  = (const float*)d_in[22];
  const float* beo1 = (const float*)d_in[23];
  const float* wo2  = (const float*)d_in[24];
  const float* bo2  = (const float*)d_in[25];

  float* ws = (float*)d_ws;
  float* h     = ws;                                   // N*H
  float* hprop = h + (size_t)N_N * H;                  // N*H (pre-loop: msg half-buffer lo)
  float* ta    = hprop + (size_t)N_N * H;              // N*H (pre-loop: msg half-buffer hi)
  float* CS    = ta + (size_t)N_N * H;                 // B*K*H
  float* acc   = CS + (size_t)B_N * K_N * H;           // small accumulators
  float* sum1 = acc,        *ssq1 = acc + 128;
  float* sc1  = acc + 256,  *sh1  = acc + 384;
  float* asum = acc + 512;
  float* G    = acc + 640;                             // 128*128
  float* sc2  = acc + 17024, *sh2 = acc + 17280;
  float* statS = acc + 17536;                          // 7 slots x 256
  float* scA = acc + 19456, *shA = acc + 19584;
  float* scB = acc + 19712, *shB = acc + 19840;
  __hip_bfloat16* x1 = (__hip_bfloat16*)(acc + 19968); // E*H bf16 (becomes a1 after k_a1_gram)

  char* p = (char*)x1 + (size_t)E_N * H * 2;
  int* cnt        = (int*)p;  p += (size_t)N_N * 4;
  int* cursor     = (int*)p;  p += (size_t)N_N * 4;
  int* rowptr     = (int*)p;  p += (size_t)N_N * 4;
  int* bsum       = (int*)p;  p += 512;
  int* bpre       = (int*)p;  p += 512;
  int* sorted_eid = (int*)p;  p += (size_t)E_N * 4;
  __hip_bfloat16* Bpack = (__hip_bfloat16*)p;  p += 65536;
  __hip_bfloat16* B1pack = (__hip_bfloat16*)p; p += 16384;

  const size_t req = (size_t)(p - (char*)d_ws);
  if (ws_size < req) return;  // diagnostic: output stays zero -> absmax == 6.396e-2

  // msg half-buffer aliases [hprop, ta] (exactly E/2*H bf16 = 2*N*H fp32 bytes)
  __hip_bfloat16* msgbuf = (__hip_bfloat16*)hprop;

  hipMemsetAsync(acc, 0, 19456 * sizeof(float), stream);
  hipMemsetAsync(cnt, 0, (size_t)N_N * sizeof(int), stream);

  // edge MLP front half + BN params
  k_packB1<<<32, 256, 0, stream>>>(w1, B1pack);
  k_gemm1_stats<<<E_N / 128, 256, 0, stream>>>(chem, B1pack, b1, x1, sum1, ssq1);
  k_bnfin<<<1, 128, 0, stream>>>(sum1, ssq1, g1, be1, 1.f / (float)E_N, sc1, sh1);
  k_a1_gram<<<512, 256, 0, stream>>>(x1, sc1, sh1, asum, G);   // also writes a1 in-place
  k_bn2fin<<<2, 256, 0, stream>>>(asum, G, w2, g2, be2, sc2, sh2);

  // sort edges by destination + pack B
  k_packB<<<128, 256, 0, stream>>>(w2, Bpack);
  k_hist<<<E_N / 256, 256, 0, stream>>>(nbr, cnt);
  k_scan1<<<128, 256, 0, stream>>>(cnt, bsum);
  k_scan2<<<1, 128, 0, stream>>>(bsum, bpre);
  k_scan3<<<128, 256, 0, stream>>>(cnt, bpre, cursor, rowptr);
  k_scatteridx<<<E_N / 256, 256, 0, stream>>>(nbr, cursor, sorted_eid);

  // msg (MFMA) + segment-sum, two halves to fit msg in the dead hprop/ta region
  for (int half = 0; half < 2; ++half) {
    const int w0 = half * (E_N / 2), w1e = w0 + E_N / 2;
    k_msg<<<(E_N / 2) / 128, 256, 0, stream>>>(x1, sorted_eid, Bpack, sc2, sh2, msgbuf, w0);
    k_segsum<<<N_N / 16, 256, 0, stream>>>(msgbuf, rowptr, cnt, h, w0, w1e, half);
  }

  float* tb = hprop;
  for (int l = 0; l < 3; ++l) {
    k_spec<<<B_N * 4, 256, 0, stream>>>(eigs, h, prop_time, l, CS);
    k_hprop<<<B_N * 16, 256, 0, stream>>>(eigs, CS, hprop);
    k_gemm<<<N_N / 128, 256, 0, stream>>>(h, hprop, pw1 + (size_t)l * H2 * H, pb1 + l * H,
                                          nullptr, nullptr, 0, H2, ta,
                                          statS + (2 * l) * 256, statS + (2 * l) * 256 + 128);
    k_bnfin<<<1, 128, 0, stream>>>(statS + (2 * l) * 256, statS + (2 * l) * 256 + 128,
                                   pg1 + l * H, pbe1 + l * H, 1.f / (float)N_N, scA, shA);
    k_gemm<<<N_N / 128, 256, 0, stream>>>(ta, nullptr, pw2 + (size_t)l * H * H, pb2 + l * H,
                                          scA, shA, 1, H, tb,
                                          statS + (2 * l + 1) * 256, statS + (2 * l + 1) * 256 + 128);
    k_bnfin<<<1, 128, 0, stream>>>(statS + (2 * l + 1) * 256, statS + (2 * l + 1) * 256 + 128,
                                   pg2 + l * H, pbe2 + l * H, 1.f / (float)N_N, scB, shB);
    k_hupd<<<N_N * H / 1024, 256, 0, stream>>>(h, tb, scB, shB);
  }

  k_gemm<<<N_N / 128, 256, 0, stream>>>(h, nullptr, wo1, bo1, nullptr, nullptr, 0, H, ta,
                                        statS + 6 * 256, statS + 6 * 256 + 128);
  k_bnfin<<<1, 128, 0, stream>>>(statS + 6 * 256, statS + 6 * 256 + 128,
                                 go1, beo1, 1.f / (float)N_N, scA, shA);
  k_head<<<B_N, 256, 0, stream>>>(ta, scA, shA, wo2, bo2, (float*)d_out);
}

// Round 5
// 3142.645 us; speedup vs baseline: 1.2999x; 1.0368x over previous
//
#include <hip/hip_runtime.h>
#include <hip/hip_bf16.h>
#include <math.h>

#define E_N 1048576
#define CF 47
#define H 128
#define H2 256
#define B_N 64
#define V_N 2048
#define K_N 128
#define N_N 131072
#define EPSf 1e-5f
#define EVS 132   // padded LDS leading dim for fp32 tiles

typedef __attribute__((ext_vector_type(8))) short short8;
typedef __attribute__((ext_vector_type(4))) float f32x4;

__device__ __forceinline__ float bf2f(unsigned int u16) {
  union { float f; unsigned int i; } x; x.i = u16 << 16; return x.f;
}
__device__ __forceinline__ unsigned int f2bf_rne(float f) {
  unsigned int u = __float_as_uint(f);
  return (u + 0x7fffu + ((u >> 16) & 1u)) >> 16;
}
__device__ __forceinline__ unsigned int packbf2(float lo, float hi) {
  return f2bf_rne(lo) | (f2bf_rne(hi) << 16);
}
__device__ __forceinline__ float frcp_(float x) { return __builtin_amdgcn_rcpf(x); }
__device__ __forceinline__ float sigmf_(float x) { return frcp_(1.f + __expf(-x)); }
__device__ __forceinline__ float siluf_(float x) { return x * sigmf_(x); }
__device__ __forceinline__ float splusf_(float x) {
  return (x > 15.f) ? x : __logf(1.f + __expf(x));
}

// pack w1 (fp32 CFx128) into bf16 B-fragment order, K padded 47->64 (zeros):
// frag idx i = ((t*2+s)*64 + L)*8 + j  holds  B[k = s*32+(L>>4)*8+j][n = t*16+(L&15)]
extern "C" __global__ void k_packB1(const float* __restrict__ w1, __hip_bfloat16* __restrict__ B1)
{
  const int i = blockIdx.x * 256 + threadIdx.x;  // 0..8191
  const int j = i & 7, L = (i >> 3) & 63, s = (i >> 9) & 1, t = i >> 10;
  const int k = s * 32 + ((L >> 4) * 8) + j;
  const int n = t * 16 + (L & 15);
  B1[i] = __float2bfloat16((k < CF) ? w1[k * H + n] : 0.f);
}

// generic W pack (K x 128 fp32, K = NS*32) into hi/lo bf16 fragment planes:
// elem i = ((t*NS+s)*64 + L)*8 + j  holds  W[k = s*32+(L>>4)*8+j][n = t*16+(L&15)]
extern "C" __global__ void k_packW(const float* __restrict__ W,
    __hip_bfloat16* __restrict__ hi, __hip_bfloat16* __restrict__ lo, const int NS)
{
  const int i = blockIdx.x * 256 + threadIdx.x;
  const int j = i & 7, L = (i >> 3) & 63, ts = i >> 9;
  const int s = ts % NS, t = ts / NS;
  const int k = s * 32 + (L >> 4) * 8 + j;
  const int n = t * 16 + (L & 15);
  const float w = W[k * H + n];
  const unsigned int h16 = f2bf_rne(w);
  ((unsigned short*)hi)[i] = (unsigned short)h16;
  ((unsigned short*)lo)[i] = (unsigned short)f2bf_rne(w - bf2f(h16));
}

// ---------------- Stage 1: x1 = chem @ w1 + b1 (E x 128) via bf16 MFMA, fused column stats ----
extern "C" __global__ __launch_bounds__(256) void k_gemm1_stats(
    const float* __restrict__ chem, const __hip_bfloat16* __restrict__ B1,
    const float* __restrict__ b1, __hip_bfloat16* __restrict__ x1,
    float* __restrict__ sum1, float* __restrict__ ssq1)
{
  __shared__ __align__(16) unsigned short As[128 * 136];
  __shared__ float bsh[128], cs[128], cq[128];
  float* Afp = (float*)As;
  const int tid = threadIdx.x;
  const int w = tid >> 6, L = tid & 63, lm = L & 15, q = L >> 4;
  const int m0 = w * 32;
  const size_t rowbase = (size_t)blockIdx.x * 128;
  if (tid < 128) { bsh[tid] = b1[tid]; cs[tid] = 0.f; cq[tid] = 0.f; }
  for (int i = tid * 4; i < 128 * CF; i += 1024)
    *(float4*)&Afp[i] = *(const float4*)&chem[rowbase * CF + i];
  __syncthreads();

  // A fragments: lane holds A[m0+mi*16+lm][s*32+q*8+j], j=0..7 (zero-padded k>=47)
  short8 fa[2][2];
  #pragma unroll
  for (int mi = 0; mi < 2; ++mi) {
    const int row = m0 + mi * 16 + lm;
    #pragma unroll
    for (int s = 0; s < 2; ++s) {
      union { unsigned int u[4]; short8 s8; } cvt;
      #pragma unroll
      for (int jp = 0; jp < 4; ++jp) {
        const int k0i = s * 32 + q * 8 + jp * 2;
        const float lo = (k0i     < CF) ? Afp[row * CF + k0i]     : 0.f;
        const float hi = (k0i + 1 < CF) ? Afp[row * CF + k0i + 1] : 0.f;
        cvt.u[jp] = packbf2(lo, hi);
      }
      fa[mi][s] = cvt.s8;
    }
  }
  __syncthreads();   // all frag reads complete before As is reused by the epilogue

  f32x4 acc[2][8];
  #pragma unroll
  for (int mi = 0; mi < 2; ++mi)
    #pragma unroll
    for (int t = 0; t < 8; ++t) acc[mi][t] = (f32x4){0.f, 0.f, 0.f, 0.f};
  const short8* bp = (const short8*)B1;
  #pragma unroll
  for (int s = 0; s < 2; ++s)
    #pragma unroll
    for (int t = 0; t < 8; ++t) {
      const short8 bf = bp[(t * 2 + s) * 64 + L];
      acc[0][t] = __builtin_amdgcn_mfma_f32_16x16x32_bf16(fa[0][s], bf, acc[0][t], 0, 0, 0);
      acc[1][t] = __builtin_amdgcn_mfma_f32_16x16x32_bf16(fa[1][s], bf, acc[1][t], 0, 0, 0);
    }

  // epilogue: bias + stats (fp32, pre-rounding) + bf16 repack into As (own rows only)
  float cs8[8], cq8[8];
  #pragma unroll
  for (int t = 0; t < 8; ++t) { cs8[t] = 0.f; cq8[t] = 0.f; }
  #pragma unroll
  for (int t = 0; t < 8; ++t) {
    const int c = t * 16 + lm;
    const float bb = bsh[c];
    #pragma unroll
    for (int mi = 0; mi < 2; ++mi)
      #pragma unroll
      for (int r = 0; r < 4; ++r) {
        const float v = acc[mi][t][r] + bb;
        cs8[t] += v; cq8[t] += v * v;
        As[(m0 + mi * 16 + q * 4 + r) * 136 + c] = (unsigned short)f2bf_rne(v);
      }
  }
  #pragma unroll
  for (int t = 0; t < 8; ++t) {
    cs8[t] += __shfl_xor(cs8[t], 16); cs8[t] += __shfl_xor(cs8[t], 32);
    cq8[t] += __shfl_xor(cq8[t], 16); cq8[t] += __shfl_xor(cq8[t], 32);
  }
  if (q == 0) {
    #pragma unroll
    for (int t = 0; t < 8; ++t) {
      atomicAdd(&cs[t * 16 + lm], cs8[t]);
      atomicAdd(&cq[t * 16 + lm], cq8[t]);
    }
  }
  __syncthreads();
  for (int i = tid; i < 128 * 16; i += 256) {
    const int r = i >> 4, cc = (i & 15) * 8;
    *(uint4*)(x1 + (rowbase + r) * H + cc) = *(const uint4*)&As[r * 136 + cc];
  }
  if (tid < 128) {
    atomicAdd(&sum1[tid], cs[tid]);
    atomicAdd(&ssq1[tid], cq[tid]);
  }
}

// BN finalize: scale/shift from sum/sumsq (biased var, matches jnp.var)
extern "C" __global__ void k_bnfin(const float* __restrict__ sum, const float* __restrict__ ssq,
    const float* __restrict__ g, const float* __restrict__ be, float invn,
    float* __restrict__ sc, float* __restrict__ sh)
{
  const int c = threadIdx.x;
  const float m = sum[c] * invn;
  const float v = ssq[c] * invn - m * m;
  const float s = g[c] * rsqrtf(v + EPSf);
  sc[c] = s;
  sh[c] = be[c] - m * s;
}

// ---------------- a1 = silu(bn1(x1)); Gram G = a1^T a1 via MFMA; writes a1 (bf16) back IN-PLACE ----
extern "C" __global__ __launch_bounds__(256) void k_a1_gram(
    __hip_bfloat16* __restrict__ x1, const float* __restrict__ sc1,
    const float* __restrict__ sh1, float* __restrict__ asum, float* __restrict__ G)
{
  __shared__ __align__(16) unsigned short frag[2][16384];   // 2 x 32 KB, double-buffered
  const int tid = threadIdx.x;
  // stage-side ids: thread owns rows [rb*8, rb*8+8) x cols [u*8, u*8+8)
  const int rb = tid >> 4, u = tid & 15;
  const int kb = rb >> 2, qw = rb & 3;
  const int th = u >> 1;                 // subtile column group 0..7
  const int cmb = (u & 1) * 8;
  const int cg = u * 8;
  // MFMA-side ids
  const int w = tid >> 6;
  const int lq = (tid >> 4) & 3;         // lane>>4 within wave
  const int cm = tid & 15;               // lane&15
  const int tib = (w >> 1) * 4, tjb = (w & 1) * 4;   // wave's 4x4 block of 16x16 G-tiles

  float scv[8], shv[8];
  #pragma unroll
  for (int jc = 0; jc < 8; ++jc) { scv[jc] = sc1[cg + jc]; shv[jc] = sh1[cg + jc]; }

  float cs8[8] = {0.f, 0.f, 0.f, 0.f, 0.f, 0.f, 0.f, 0.f};
  f32x4 acc[4][4];
  #pragma unroll
  for (int a = 0; a < 4; ++a)
    #pragma unroll
    for (int b = 0; b < 4; ++b) acc[a][b] = (f32x4){0.f, 0.f, 0.f, 0.f};

  const int ldsbase = kb * 4096 + th * 512 + qw * 128;
  uint4 rv[8];

  // silu + colsum + bf16 pack + global write-back + frag-LDS write of the 8x8 block in rv
  auto PROCESS = [&](int bsel, size_t tb) {
    unsigned int colw[8][4];
    #pragma unroll
    for (int jc = 0; jc < 8; ++jc) { colw[jc][0] = 0; colw[jc][1] = 0; colw[jc][2] = 0; colw[jc][3] = 0; }
    #pragma unroll
    for (int j8 = 0; j8 < 8; ++j8) {
      const uint4 pk = rv[j8];
      float f[8];
      f[0] = bf2f(pk.x & 0xffff); f[1] = bf2f(pk.x >> 16);
      f[2] = bf2f(pk.y & 0xffff); f[3] = bf2f(pk.y >> 16);
      f[4] = bf2f(pk.z & 0xffff); f[5] = bf2f(pk.z >> 16);
      f[6] = bf2f(pk.w & 0xffff); f[7] = bf2f(pk.w >> 16);
      unsigned int bfv[8];
      #pragma unroll
      for (int jc = 0; jc < 8; ++jc) {
        f[jc] = siluf_(f[jc] * scv[jc] + shv[jc]);
        cs8[jc] += f[jc];
        bfv[jc] = f2bf_rne(f[jc]);
        colw[jc][j8 >> 1] |= bfv[jc] << (16 * (j8 & 1));
      }
      uint4 o;
      o.x = bfv[0] | (bfv[1] << 16); o.y = bfv[2] | (bfv[3] << 16);
      o.z = bfv[4] | (bfv[5] << 16); o.w = bfv[6] | (bfv[7] << 16);
      *(uint4*)(x1 + (tb + (size_t)(rb * 8 + j8)) * H + cg) = o;
    }
    #pragma unroll
    for (int jc = 0; jc < 8; ++jc) {
      const int pos = (cmb + jc + 2 * th) & 15;
      uint4 cw;
      cw.x = colw[jc][0]; cw.y = colw[jc][1]; cw.z = colw[jc][2]; cw.w = colw[jc][3];
      *(uint4*)&frag[bsel][ldsbase + pos * 8] = cw;
    }
  };

  // prologue: tile 0 -> buf 0
  {
    const size_t tb = (size_t)blockIdx.x * 128;
    #pragma unroll
    for (int j8 = 0; j8 < 8; ++j8)
      rv[j8] = *(const uint4*)(x1 + (tb + (size_t)(rb * 8 + j8)) * H + cg);
    PROCESS(0, tb);
  }

  for (int k = 0; k < 16; ++k) {
    __syncthreads();
    const int cur = k & 1;
    const bool hasnext = (k + 1 < 16);
    const size_t tbn = (size_t)(blockIdx.x + (k + 1) * 512) * 128;
    if (hasnext) {
      #pragma unroll
      for (int j8 = 0; j8 < 8; ++j8)
        rv[j8] = *(const uint4*)(x1 + (tbn + (size_t)(rb * 8 + j8)) * H + cg);
    }
    // MFMA on current buffer (hides next tile's global-load latency)
    #pragma unroll
    for (int kk = 0; kk < 4; ++kk) {
      short8 fa[4], fb[4];
      #pragma unroll
      for (int a = 0; a < 4; ++a) {
        const int T = tib + a;
        fa[a] = *(const short8*)&frag[cur][kk * 4096 + T * 512 + lq * 128 + ((cm + 2 * T) & 15) * 8];
      }
      #pragma unroll
      for (int b = 0; b < 4; ++b) {
        const int T = tjb + b;
        fb[b] = *(const short8*)&frag[cur][kk * 4096 + T * 512 + lq * 128 + ((cm + 2 * T) & 15) * 8];
      }
      #pragma unroll
      for (int a = 0; a < 4; ++a)
        #pragma unroll
        for (int b = 0; b < 4; ++b)
          acc[a][b] = __builtin_amdgcn_mfma_f32_16x16x32_bf16(fa[a], fb[b], acc[a][b], 0, 0, 0);
    }
    if (hasnext) PROCESS(cur ^ 1, tbn);
  }

  // colsum: reduce over the 4 row-block groups sharing this thread's 8 columns
  #pragma unroll
  for (int jc = 0; jc < 8; ++jc) {
    cs8[jc] += __shfl_xor(cs8[jc], 16);
    cs8[jc] += __shfl_xor(cs8[jc], 32);
  }
  __syncthreads();                       // frag no longer needed: reuse as fp32 scratch
  float* redp = (float*)&frag[0][0];
  if ((tid & 63) < 16) {
    #pragma unroll
    for (int jc = 0; jc < 8; ++jc) redp[w * 128 + (tid & 15) * 8 + jc] = cs8[jc];
  }
  __syncthreads();
  if (tid < 128)
    atomicAdd(&asum[tid], redp[tid] + redp[128 + tid] + redp[256 + tid] + redp[384 + tid]);

  // G: C/D layout col=lane&15, row=(lane>>4)*4+reg
  #pragma unroll
  for (int a = 0; a < 4; ++a)
    #pragma unroll
    for (int b = 0; b < 4; ++b)
      #pragma unroll
      for (int r = 0; r < 4; ++r)
        atomicAdd(&G[((tib + a) * 16 + lq * 4 + r) * 128 + (tjb + b) * 16 + cm], acc[a][b][r]);
}

// BN2 stats WITHOUT materializing x2: var_j = w2col^T (G/E) w2col - (mu.w2col)^2
extern "C" __global__ __launch_bounds__(256) void k_bn2fin(
    const float* __restrict__ asum, const float* __restrict__ Gm,
    const float* __restrict__ w2, const float* __restrict__ g2,
    const float* __restrict__ be2, float* __restrict__ sc2, float* __restrict__ sh2)
{
  __shared__ float Gs[128 * 128];
  __shared__ float w2s[128 * 128];
  __shared__ float mus[128];
  __shared__ float red[512];
  const int tid = threadIdx.x;
  const int jbase = blockIdx.x * 128;
  for (int i = tid; i < 128 * 128; i += 256) {
    Gs[i] = Gm[i];
    w2s[i] = w2[(i >> 7) * H2 + jbase + (i & 127)];
  }
  if (tid < 128) mus[tid] = asum[tid] * (1.f / (float)E_N);
  __syncthreads();
  const int jj = tid & 127, ih = tid >> 7;
  float m1 = 0.f, q = 0.f;
  for (int i = ih * 64; i < ih * 64 + 64; ++i) {
    const float wi = w2s[i * 128 + jj];
    m1 += mus[i] * wi;
    float si = 0.f;
    #pragma unroll 4
    for (int k = 0; k < 128; ++k) si += Gs[i * 128 + k] * w2s[k * 128 + jj];
    q += wi * si;
  }
  red[tid] = m1; red[256 + tid] = q;
  __syncthreads();
  if (ih == 0) {
    const float m1t = red[jj] + red[jj + 128];
    const float qt  = red[256 + jj] + red[256 + jj + 128];
    const float var = qt * (1.f / (float)E_N) - m1t * m1t;
    const float s = g2[jbase + jj] * rsqrtf(var + EPSf);
    sc2[jbase + jj] = s;
    sh2[jbase + jj] = be2[jbase + jj] - m1t * s;
  }
}

// ---------------- Edge sort by destination: histogram / scan / scatter ----------------
extern "C" __global__ __launch_bounds__(256) void k_hist(
    const int* __restrict__ nbr, int* __restrict__ cnt)
{
  const int e = blockIdx.x * 256 + threadIdx.x;
  atomicAdd(&cnt[nbr[e]], 1);
}

extern "C" __global__ __launch_bounds__(256) void k_scan1(
    const int* __restrict__ cnt, int* __restrict__ bsum)
{
  __shared__ int rs[256];
  const int tid = threadIdx.x, b = blockIdx.x;
  const int4 c = *(const int4*)&cnt[b * 1024 + tid * 4];
  rs[tid] = c.x + c.y + c.z + c.w;
  __syncthreads();
  for (int o = 128; o > 0; o >>= 1) {
    if (tid < o) rs[tid] += rs[tid + o];
    __syncthreads();
  }
  if (tid == 0) bsum[b] = rs[0];
}

extern "C" __global__ void k_scan2(const int* __restrict__ bsum, int* __restrict__ bpre)
{
  __shared__ int bs[128];
  const int tid = threadIdx.x;
  bs[tid] = bsum[tid];
  __syncthreads();
  int p = 0;
  for (int i = 0; i < tid; ++i) p += bs[i];
  bpre[tid] = p;
}

extern "C" __global__ __launch_bounds__(256) void k_scan3(
    const int* __restrict__ cnt, const int* __restrict__ bpre,
    int* __restrict__ cursor, int* __restrict__ rowptr)
{
  __shared__ int tsum[256];
  const int tid = threadIdx.x, b = blockIdx.x;
  const int4 c = *(const int4*)&cnt[b * 1024 + tid * 4];
  const int t1 = c.x, t2 = c.x + c.y, t3 = c.x + c.y + c.z, tot = t3 + c.w;
  tsum[tid] = tot;
  __syncthreads();
  for (int o = 1; o < 256; o <<= 1) {
    const int add = (tid >= o) ? tsum[tid - o] : 0;
    __syncthreads();
    tsum[tid] += add;
    __syncthreads();
  }
  const int excl = (tid == 0) ? 0 : tsum[tid - 1];
  const int base = bpre[b] + excl;
  int4 o4;
  o4.x = base; o4.y = base + t1; o4.z = base + t2; o4.w = base + t3;
  *(int4*)&cursor[b * 1024 + tid * 4] = o4;
  *(int4*)&rowptr[b * 1024 + tid * 4] = o4;
}

extern "C" __global__ __launch_bounds__(256) void k_scatteridx(
    const int* __restrict__ nbr, int* __restrict__ cursor,
    int* __restrict__ sorted_eid)
{
  const int e = blockIdx.x * 256 + threadIdx.x;
  const int v = nbr[e];
  const int pos = atomicAdd(&cursor[v], 1);
  sorted_eid[pos] = e;
}

// pack w2 (fp32 128x256 row-major) into bf16 B-fragment order:
// frag idx i = ((t*4+s)*64 + L)*8 + j  holds  B[k = s*32+(L>>4)*8+j][n = t*16+(L&15)]
extern "C" __global__ void k_packB(const float* __restrict__ w2, __hip_bfloat16* __restrict__ Bpack)
{
  const int i = blockIdx.x * 256 + threadIdx.x;  // 0..32767
  const int j = i & 7, L = (i >> 3) & 63, s = (i >> 9) & 3, t = i >> 11;
  const int k = s * 32 + (L >> 4) * 8 + j;
  const int n = t * 16 + (L & 15);
  Bpack[i] = __float2bfloat16(w2[k * H2 + n]);
}

// ---------------- MFMA msg kernel: 128 sorted edges/block -> msg rows (bf16) ----------------
extern "C" __global__ __launch_bounds__(256) void k_msg(
    const __hip_bfloat16* __restrict__ a1, const int* __restrict__ sorted_eid,
    const __hip_bfloat16* __restrict__ Bpack,
    const float* __restrict__ sc2, const float* __restrict__ sh2,
    __hip_bfloat16* __restrict__ msgbuf, const int eoff)
{
  __shared__ __hip_bfloat16 As[128 * 136];   // a1 tile; reused for msg repack
  __shared__ int eidsh[128];
  __shared__ float sc2s[256], sh2s[256];
  const int tid = threadIdx.x;
  const int s0 = blockIdx.x * 128;           // row base within this half
  if (tid < 128) eidsh[tid] = sorted_eid[eoff + s0 + tid];
  sc2s[tid] = sc2[tid]; sh2s[tid] = sh2[tid];
  __syncthreads();
  // gather a1 rows (pre-activated bf16): 16 uint4 per row
  for (int i = tid; i < 128 * 16; i += 256) {
    const int r = i >> 4, cc = (i & 15) * 8;
    *(uint4*)&As[r * 136 + cc] = *(const uint4*)(a1 + (size_t)eidsh[r] * H + cc);
  }
  __syncthreads();
  const int w = tid >> 6, L = tid & 63, lm = L & 15, q = L >> 4;
  const int m0 = w * 32, m1 = w * 32 + 16;
  f32x4 acc0[16], acc1[16];
  #pragma unroll
  for (int t = 0; t < 16; ++t) { acc0[t] = (f32x4){0.f,0.f,0.f,0.f}; acc1[t] = (f32x4){0.f,0.f,0.f,0.f}; }
  const short8* bp = (const short8*)Bpack;
  #pragma unroll
  for (int s = 0; s < 4; ++s) {
    const short8 af0 = *(const short8*)&As[(m0 + lm) * 136 + s * 32 + q * 8];
    const short8 af1 = *(const short8*)&As[(m1 + lm) * 136 + s * 32 + q * 8];
    #pragma unroll
    for (int t = 0; t < 16; ++t) {
      const short8 bf = bp[(t * 4 + s) * 64 + L];
      acc0[t] = __builtin_amdgcn_mfma_f32_16x16x32_bf16(af0, bf, acc0[t], 0, 0, 0);
      acc1[t] = __builtin_amdgcn_mfma_f32_16x16x32_bf16(af1, bf, acc1[t], 0, 0, 0);
    }
  }
  // epilogue: rows [w*32, w*32+32) belong exclusively to this wave -> safe to overwrite As
  #pragma unroll
  for (int t = 0; t < 8; ++t) {
    const int cF = t * 16 + lm;
    const float scF = sc2s[cF], shF = sh2s[cF];
    const float scC = sc2s[128 + cF], shC = sh2s[128 + cF];
    #pragma unroll
    for (int r = 0; r < 4; ++r) {
      const int row0 = m0 + q * 4 + r, row1 = m1 + q * 4 + r;
      const float f0 = acc0[t][r] * scF + shF;
      const float g0 = acc0[t + 8][r] * scC + shC;
      const float f1 = acc1[t][r] * scF + shF;
      const float g1 = acc1[t + 8][r] * scC + shC;
      ((unsigned short*)As)[row0 * 136 + cF] = (unsigned short)f2bf_rne(sigmf_(f0) * splusf_(g0));
      ((unsigned short*)As)[row1 * 136 + cF] = (unsigned short)f2bf_rne(sigmf_(f1) * splusf_(g1));
    }
  }
  __syncthreads();
  // coalesced store of msg rows
  for (int i = tid; i < 128 * 16; i += 256) {
    const int r = i >> 4, cc = (i & 15) * 8;
    *(uint4*)(msgbuf + ((size_t)(s0 + r)) * H + cc) = *(const uint4*)&As[r * 136 + cc];
  }
}

// ---------------- Segment sum over sorted msg rows: NO atomics, each node owned by one group ----------------
extern "C" __global__ __launch_bounds__(256) void k_segsum(
    const __hip_bfloat16* __restrict__ msgbuf, const int* __restrict__ rowptr,
    const int* __restrict__ cnt, float* __restrict__ h,
    const int w0, const int w1, const int mode)
{
  __shared__ float redA[256], redB[256];
  const int tid = threadIdx.x;
  const int c2 = (tid & 63) * 2;   // column pair
  const int j  = tid >> 6;         // 4-way row split
  const int n0 = blockIdx.x * 16;
  for (int g = 0; g < 16; ++g) {
    const int n = n0 + g;
    const int s = rowptr[n], e = s + cnt[n];
    const int lo = max(s, w0), hi = min(e, w1);
    float s0 = 0.f, s1 = 0.f;
    for (int r = lo + j; r < hi; r += 4) {
      const unsigned int pk = *(const unsigned int*)(msgbuf + ((size_t)(r - w0)) * H + c2);
      s0 += bf2f(pk & 0xffff);
      s1 += bf2f(pk >> 16);
    }
    redA[tid] = s0; redB[tid] = s1;
    __syncthreads();
    if (j == 0) {
      const int t = tid;  // 0..63
      const float t0 = redA[t] + redA[t + 64] + redA[t + 128] + redA[t + 192];
      const float t1 = redB[t] + redB[t + 64] + redB[t + 128] + redB[t + 192];
      float* hp = h + (size_t)n * H + c2;
      if (mode == 0) { hp[0] = t0; hp[1] = t1; }
      else           { hp[0] += t0; hp[1] += t1; }
    }
    __syncthreads();
  }
}

// ---------------- Spectral: CS[b,k,h] = exp(-ev[b,k]*time[h]) * sum_v evinv[b,k,v] h[b,v,h] ----------------
extern "C" __global__ __launch_bounds__(256) void k_spec(
    const float* __restrict__ eigs, const float* __restrict__ h,
    const float* __restrict__ prop_time, int l, float* __restrict__ CS)
{
  __shared__ float Ash[64 * 32];
  __shared__ float Hsh[64 * 128];
  const int tid = threadIdx.x;
  const int b = blockIdx.x >> 2;
  const int kbase = (blockIdx.x & 3) * 32;
  const int k0 = (tid >> 5) * 4;
  const int c0 = (tid & 31) * 4;
  const size_t ebase = (size_t)b * (4097 * 128);
  float acc[4][4] = {};
  for (int vb = 0; vb < V_N; vb += 64) {
    __syncthreads();
    for (int i = tid * 4; i < 64 * 32; i += 1024) {
      const int vv = i >> 5, kk = i & 31;
      *(float4*)&Ash[i] = *(const float4*)&eigs[ebase + (size_t)(2049 + vb + vv) * 128 + kbase + kk];
    }
    for (int i = tid * 4; i < 64 * 128; i += 1024)
      *(float4*)&Hsh[i] = *(const float4*)&h[((size_t)b * V_N + vb) * 128 + i];
    __syncthreads();
    for (int vv = 0; vv < 64; ++vv) {
      const float4 av = *(const float4*)&Ash[vv * 32 + k0];
      const float4 hv = *(const float4*)&Hsh[vv * 128 + c0];
      const float aa[4] = {av.x, av.y, av.z, av.w};
      const float hh[4] = {hv.x, hv.y, hv.z, hv.w};
      #pragma unroll
      for (int a = 0; a < 4; ++a)
        #pragma unroll
        for (int j = 0; j < 4; ++j) acc[a][j] += aa[a] * hh[j];
    }
  }
  #pragma unroll
  for (int a = 0; a < 4; ++a) {
    const float ev = eigs[ebase + kbase + k0 + a];
    #pragma unroll
    for (int j = 0; j < 4; ++j) {
      const float tm = fmaxf(prop_time[l * H + c0 + j], 1e-6f);
      CS[((size_t)b * K_N + kbase + k0 + a) * H + c0 + j] = __expf(-ev * tm) * acc[a][j];
    }
  }
}

// h_prop[b,v,h] = sum_k evecs[b,v,k] * CS[b,k,h]
extern "C" __global__ __launch_bounds__(256) void k_hprop(
    const float* __restrict__ eigs, const float* __restrict__ CS,
    float* __restrict__ hprop)
{
  __shared__ float EvT[32 * EVS];
  __shared__ float CSsh[32 * 128];
  const int tid = threadIdx.x;
  const int b = blockIdx.x >> 4;
  const int vbase = (blockIdx.x & 15) * 128;
  const int v0 = (tid >> 4) * 8;
  const int c0 = (tid & 15) * 8;
  const size_t ebase = (size_t)b * (4097 * 128);
  float acc[8][8] = {};
  for (int kb = 0; kb < K_N; kb += 32) {
    __syncthreads();
    for (int i = tid; i < 128 * 32; i += 256) {
      const int vv = i >> 5, kk = i & 31;
      EvT[kk * EVS + vv] = eigs[ebase + (size_t)(1 + vbase + vv) * 128 + kb + kk];
    }
    for (int i = tid * 4; i < 32 * 128; i += 1024)
      *(float4*)&CSsh[i] = *(const float4*)&CS[((size_t)b * K_N + kb) * 128 + i];
    __syncthreads();
    for (int kk = 0; kk < 32; ++kk) {
      const float4 ea = *(const float4*)&EvT[kk * EVS + v0];
      const float4 eb = *(const float4*)&EvT[kk * EVS + v0 + 4];
      const float4 ca = *(const float4*)&CSsh[kk * 128 + c0];
      const float4 cb = *(const float4*)&CSsh[kk * 128 + c0 + 4];
      const float ee[8] = {ea.x, ea.y, ea.z, ea.w, eb.x, eb.y, eb.z, eb.w};
      const float cc[8] = {ca.x, ca.y, ca.z, ca.w, cb.x, cb.y, cb.z, cb.w};
      #pragma unroll
      for (int a = 0; a < 8; ++a)
        #pragma unroll
        for (int j = 0; j < 8; ++j) acc[a][j] += ee[a] * cc[j];
    }
  }
  #pragma unroll
  for (int a = 0; a < 8; ++a) {
    const size_t row = ((size_t)b * V_N + vbase + v0 + a) * H;
    #pragma unroll
    for (int j = 0; j < 8; j += 4) {
      float4 o;
      o.x = acc[a][j]; o.y = acc[a][j+1]; o.z = acc[a][j+2]; o.w = acc[a][j+3];
      *(float4*)&hprop[row + c0 + j] = o;
    }
  }
}

// ---------------- MFMA 128-col GEMM (bf16x3 split = fp32-accurate) with FUSED column stats ----
// A (fp32, optional BN+silu preop) staged per-128-k-half into hi/lo bf16 LDS planes
// ([128][136], k_msg layout). W pre-packed hi/lo fragment planes (k_packW). Per (s,t):
// acc += Ahi*Whi + Ahi*Wlo + Alo*Whi  (drops ~2^-16-rel lo*lo term).
extern "C" __global__ __launch_bounds__(256) void k_gemmM(
    const float* __restrict__ A0, const float* __restrict__ A1,
    const __hip_bfloat16* __restrict__ Whi, const __hip_bfloat16* __restrict__ Wlo,
    const float* __restrict__ bias, const float* __restrict__ preSc,
    const float* __restrict__ preSh, const int preop, const int KcA,
    float* __restrict__ out, float* __restrict__ sum, float* __restrict__ ssq)
{
  __shared__ __align__(16) unsigned short Ahi[128 * 136];
  __shared__ __align__(16) unsigned short Alo[128 * 136];
  __shared__ float bsh[128], cs[128], cq[128];
  const int tid = threadIdx.x;
  const int w = tid >> 6, L = tid & 63, lm = L & 15, q = L >> 4;
  const int m0 = w * 32;
  const int rbase = blockIdx.x * 128;
  const int NS = KcA >> 5;
  if (tid < 128) { bsh[tid] = bias[tid]; cs[tid] = 0.f; cq[tid] = 0.f; }

  f32x4 acc[2][8];
  #pragma unroll
  for (int mi = 0; mi < 2; ++mi)
    #pragma unroll
    for (int t = 0; t < 8; ++t) acc[mi][t] = (f32x4){0.f, 0.f, 0.f, 0.f};

  const short8* bhp = (const short8*)Whi;
  const short8* blp = (const short8*)Wlo;

  for (int hf = 0; hf < (KcA >> 7); ++hf) {
    const float* __restrict__ Asrc = (hf == 0) ? A0 : A1;
    __syncthreads();   // previous half's frag reads complete before restage
    for (int i = tid * 4; i < 128 * 128; i += 1024) {
      const int rr = i >> 7, kk = i & 127;
      const float4 v4 = *(const float4*)&Asrc[((size_t)rbase + rr) * H + kk];
      float v[4] = {v4.x, v4.y, v4.z, v4.w};
      unsigned int h4[4], l4[4];
      #pragma unroll
      for (int e = 0; e < 4; ++e) {
        float vv = v[e];
        if (preop) { vv = vv * preSc[kk + e] + preSh[kk + e]; vv = siluf_(vv); }
        h4[e] = f2bf_rne(vv);
        l4[e] = f2bf_rne(vv - bf2f(h4[e]));
      }
      uint2 ph, pl;
      ph.x = h4[0] | (h4[1] << 16); ph.y = h4[2] | (h4[3] << 16);
      pl.x = l4[0] | (l4[1] << 16); pl.y = l4[2] | (l4[3] << 16);
      *(uint2*)&Ahi[rr * 136 + kk] = ph;
      *(uint2*)&Alo[rr * 136 + kk] = pl;
    }
    __syncthreads();
    #pragma unroll
    for (int s = 0; s < 4; ++s) {
      short8 ah[2], al[2];
      #pragma unroll
      for (int mi = 0; mi < 2; ++mi) {
        const int row = m0 + mi * 16 + lm;
        ah[mi] = *(const short8*)&Ahi[row * 136 + s * 32 + q * 8];
        al[mi] = *(const short8*)&Alo[row * 136 + s * 32 + q * 8];
      }
      #pragma unroll
      for (int t = 0; t < 8; ++t) {
        const int bidx = (t * NS + hf * 4 + s) * 64 + L;
        const short8 bh = bhp[bidx];
        const short8 bl = blp[bidx];
        #pragma unroll
        for (int mi = 0; mi < 2; ++mi) {
          acc[mi][t] = __builtin_amdgcn_mfma_f32_16x16x32_bf16(ah[mi], bh, acc[mi][t], 0, 0, 0);
          acc[mi][t] = __builtin_amdgcn_mfma_f32_16x16x32_bf16(ah[mi], bl, acc[mi][t], 0, 0, 0);
          acc[mi][t] = __builtin_amdgcn_mfma_f32_16x16x32_bf16(al[mi], bh, acc[mi][t], 0, 0, 0);
        }
      }
    }
  }

  // epilogue: bias + stats + fp32 store (C layout: col=t*16+lm, row=m0+mi*16+q*4+r)
  float cs8[8], cq8[8];
  #pragma unroll
  for (int t = 0; t < 8; ++t) { cs8[t] = 0.f; cq8[t] = 0.f; }
  #pragma unroll
  for (int t = 0; t < 8; ++t) {
    const int c = t * 16 + lm;
    const float bb = bsh[c];
    #pragma unroll
    for (int mi = 0; mi < 2; ++mi)
      #pragma unroll
      for (int r = 0; r < 4; ++r) {
        const float v = acc[mi][t][r] + bb;
        cs8[t] += v; cq8[t] += v * v;
        out[((size_t)rbase + m0 + mi * 16 + q * 4 + r) * H + c] = v;
      }
  }
  #pragma unroll
  for (int t = 0; t < 8; ++t) {
    cs8[t] += __shfl_xor(cs8[t], 16); cs8[t] += __shfl_xor(cs8[t], 32);
    cq8[t] += __shfl_xor(cq8[t], 16); cq8[t] += __shfl_xor(cq8[t], 32);
  }
  if (q == 0) {
    #pragma unroll
    for (int t = 0; t < 8; ++t) {
      atomicAdd(&cs[t * 16 + lm], cs8[t]);
      atomicAdd(&cq[t * 16 + lm], cq8[t]);
    }
  }
  __syncthreads();
  if (tid < 128) {
    atomicAdd(&sum[tid], cs[tid]);
    atomicAdd(&ssq[tid], cq[tid]);
  }
}

// h += sc*tb + sh (residual with BN applied)
extern "C" __global__ __launch_bounds__(256) void k_hupd(
    float* __restrict__ h, const float* __restrict__ tb,
    const float* __restrict__ sc, const float* __restrict__ sh)
{
  const int i4 = blockIdx.x * 256 + threadIdx.x;
  const size_t base = (size_t)i4 * 4;
  const int c = (int)(base & 127);
  float4 t = *(const float4*)&tb[base];
  float4 hh = *(const float4*)&h[base];
  hh.x += sc[c+0]*t.x + sh[c+0];
  hh.y += sc[c+1]*t.y + sh[c+1];
  hh.z += sc[c+2]*t.z + sh[c+2];
  hh.w += sc[c+3]*t.w + sh[c+3];
  *(float4*)&h[base] = hh;
}

// head: out[b] = mean_v( silu(bn(ta_row)) . wo2 ) + bo2
extern "C" __global__ __launch_bounds__(256) void k_head(
    const float* __restrict__ ta, const float* __restrict__ sc,
    const float* __restrict__ sh, const float* __restrict__ wo2,
    const float* __restrict__ bo2, float* __restrict__ out)
{
  __shared__ float w2s[128], scs[128], shs[128];
  __shared__ float wred[4];
  const int tid = threadIdx.x;
  if (tid < 128) { w2s[tid] = wo2[tid]; scs[tid] = sc[tid]; shs[tid] = sh[tid]; }
  __syncthreads();
  const int b = blockIdx.x;
  const int wave = tid >> 6, lane = tid & 63;
  const int j = lane * 2;
  const float w0 = w2s[j], w1 = w2s[j+1];
  const float s0 = scs[j], s1 = scs[j+1], t0 = shs[j], t1 = shs[j+1];
  float p = 0.f;
  for (int v = wave; v < V_N; v += 4) {
    const float2 xv = *(const float2*)&ta[((size_t)b * V_N + v) * H + j];
    float x0 = xv.x * s0 + t0; x0 = siluf_(x0);
    float x1 = xv.y * s1 + t1; x1 = siluf_(x1);
    p += x0 * w0 + x1 * w1;
  }
  #pragma unroll
  for (int off = 32; off > 0; off >>= 1) p += __shfl_down(p, off);
  if (lane == 0) wred[wave] = p;
  __syncthreads();
  if (tid == 0) out[b] = (wred[0] + wred[1] + wred[2] + wred[3]) * (1.f / V_N) + bo2[0];
}

extern "C" void kernel_launch(void* const* d_in, const int* in_sizes, int n_in,
                              void* d_out, int out_size, void* d_ws, size_t ws_size,
                              hipStream_t stream) {
  (void)in_sizes; (void)n_in; (void)out_size;
  const float* chem = (const float*)d_in[0];
  const int*   nbr  = (const int*)d_in[1];
  const float* eigs = (const float*)d_in[2];
  const float* w1   = (const float*)d_in[3];
  const float* b1   = (const float*)d_in[4];
  const float* g1   = (const float*)d_in[5];
  const float* be1  = (const float*)d_in[6];
  const float* w2   = (const float*)d_in[7];
  const float* b2   = (const float*)d_in[8];  (void)b2;  // cancels through BN mean
  const float* g2   = (const float*)d_in[9];
  const float* be2  = (const float*)d_in[10];
  const float* prop_time = (const float*)d_in[11];
  const float* pw1  = (const float*)d_in[12];
  const float* pb1  = (const float*)d_in[13];
  const float* pg1  = (const float*)d_in[14];
  const float* pbe1 = (const float*)d_in[15];
  const float* pw2  = (const float*)d_in[16];
  const float* pb2  = (const float*)d_in[17];
  const float* pg2  = (const float*)d_in[18];
  const float* pbe2 = (const float*)d_in[19];
  const float* wo1  = (const float*)d_in[20];
  const float* bo1  = (const float*)d_in[21];
  const float* go1  = (const float*)d_in[22];
  const float* beo1 = (const float*)d_in[23];
  const float* wo2  = (const float*)d_in[24];
  const float* bo2  = (const float*)d_in[25];

  float* ws = (float*)d_ws;
  float* h     = ws;                                   // N*H
  float* hprop = h + (size_t)N_N * H;                  // N*H (pre-loop: msg half-buffer lo)
  float* ta    = hprop + (size_t)N_N * H;              // N*H (pre-loop: msg half-buffer hi)
  float* CS    = ta + (size_t)N_N * H;                 // B*K*H
  float* acc   = CS + (size_t)B_N * K_N * H;           // small accumulators
  float* sum1 = acc,        *ssq1 = acc + 128;
  float* sc1  = acc + 256,  *sh1  = acc + 384;
  float* asum = acc + 512;
  float* G    = acc + 640;                             // 128*128
  float* sc2  = acc + 17024, *sh2 = acc + 17280;
  float* statS = acc + 17536;                          // 7 slots x 256
  float* scA = acc + 19456, *shA = acc + 19584;
  float* scB = acc + 19712, *shB = acc + 19840;
  __hip_bfloat16* x1 = (__hip_bfloat16*)(acc + 19968); // E*H bf16 (becomes a1 after k_a1_gram)

  char* p = (char*)x1 + (size_t)E_N * H * 2;
  int* cnt        = (int*)p;  p += (size_t)N_N * 4;
  int* cursor     = (int*)p;  p += (size_t)N_N * 4;
  int* rowptr     = (int*)p;  p += (size_t)N_N * 4;
  int* bsum       = (int*)p;  p += 512;
  int* bpre       = (int*)p;  p += 512;
  int* sorted_eid = (int*)p;  p += (size_t)E_N * 4;
  __hip_bfloat16* Bpack = (__hip_bfloat16*)p;  p += 65536;
  __hip_bfloat16* B1pack = (__hip_bfloat16*)p; p += 16384;
  __hip_bfloat16* PW1hi = (__hip_bfloat16*)p;  p += 3 * 65536;   // 3 x 256x128 bf16
  __hip_bfloat16* PW1lo = (__hip_bfloat16*)p;  p += 3 * 65536;
  __hip_bfloat16* PW2hi = (__hip_bfloat16*)p;  p += 3 * 32768;   // 3 x 128x128 bf16
  __hip_bfloat16* PW2lo = (__hip_bfloat16*)p;  p += 3 * 32768;
  __hip_bfloat16* WO1hi = (__hip_bfloat16*)p;  p += 32768;
  __hip_bfloat16* WO1lo = (__hip_bfloat16*)p;  p += 32768;

  const size_t req = (size_t)(p - (char*)d_ws);
  if (ws_size < req) return;  // diagnostic: output stays zero -> absmax == 6.396e-2

  // msg half-buffer aliases [hprop, ta] (exactly E/2*H bf16 = 2*N*H fp32 bytes)
  __hip_bfloat16* msgbuf = (__hip_bfloat16*)hprop;

  hipMemsetAsync(acc, 0, 19456 * sizeof(float), stream);
  hipMemsetAsync(cnt, 0, (size_t)N_N * sizeof(int), stream);

  // edge MLP front half + BN params
  k_packB1<<<32, 256, 0, stream>>>(w1, B1pack);
  k_gemm1_stats<<<E_N / 128, 256, 0, stream>>>(chem, B1pack, b1, x1, sum1, ssq1);
  k_bnfin<<<1, 128, 0, stream>>>(sum1, ssq1, g1, be1, 1.f / (float)E_N, sc1, sh1);
  k_a1_gram<<<512, 256, 0, stream>>>(x1, sc1, sh1, asum, G);   // also writes a1 in-place
  k_bn2fin<<<2, 256, 0, stream>>>(asum, G, w2, g2, be2, sc2, sh2);

  // sort edges by destination + pack B / propagation weights
  k_packB<<<128, 256, 0, stream>>>(w2, Bpack);
  for (int l = 0; l < 3; ++l) {
    k_packW<<<128, 256, 0, stream>>>(pw1 + (size_t)l * H2 * H, PW1hi + (size_t)l * 32768,
                                     PW1lo + (size_t)l * 32768, 8);
    k_packW<<<64, 256, 0, stream>>>(pw2 + (size_t)l * H * H, PW2hi + (size_t)l * 16384,
                                    PW2lo + (size_t)l * 16384, 4);
  }
  k_packW<<<64, 256, 0, stream>>>(wo1, WO1hi, WO1lo, 4);
  k_hist<<<E_N / 256, 256, 0, stream>>>(nbr, cnt);
  k_scan1<<<128, 256, 0, stream>>>(cnt, bsum);
  k_scan2<<<1, 128, 0, stream>>>(bsum, bpre);
  k_scan3<<<128, 256, 0, stream>>>(cnt, bpre, cursor, rowptr);
  k_scatteridx<<<E_N / 256, 256, 0, stream>>>(nbr, cursor, sorted_eid);

  // msg (MFMA) + segment-sum, two halves to fit msg in the dead hprop/ta region
  for (int half = 0; half < 2; ++half) {
    const int w0 = half * (E_N / 2), w1e = w0 + E_N / 2;
    k_msg<<<(E_N / 2) / 128, 256, 0, stream>>>(x1, sorted_eid, Bpack, sc2, sh2, msgbuf, w0);
    k_segsum<<<N_N / 16, 256, 0, stream>>>(msgbuf, rowptr, cnt, h, w0, w1e, half);
  }

  float* tb = hprop;
  for (int l = 0; l < 3; ++l) {
    k_spec<<<B_N * 4, 256, 0, stream>>>(eigs, h, prop_time, l, CS);
    k_hprop<<<B_N * 16, 256, 0, stream>>>(eigs, CS, hprop);
    k_gemmM<<<N_N / 128, 256, 0, stream>>>(h, hprop, PW1hi + (size_t)l * 32768,
                                           PW1lo + (size_t)l * 32768, pb1 + l * H,
                                           nullptr, nullptr, 0, H2, ta,
                                           statS + (2 * l) * 256, statS + (2 * l) * 256 + 128);
    k_bnfin<<<1, 128, 0, stream>>>(statS + (2 * l) * 256, statS + (2 * l) * 256 + 128,
                                   pg1 + l * H, pbe1 + l * H, 1.f / (float)N_N, scA, shA);
    k_gemmM<<<N_N / 128, 256, 0, stream>>>(ta, nullptr, PW2hi + (size_t)l * 16384,
                                           PW2lo + (size_t)l * 16384, pb2 + l * H,
                                           scA, shA, 1, H, tb,
                                           statS + (2 * l + 1) * 256, statS + (2 * l + 1) * 256 + 128);
    k_bnfin<<<1, 128, 0, stream>>>(statS + (2 * l + 1) * 256, statS + (2 * l + 1) * 256 + 128,
                                   pg2 + l * H, pbe2 + l * H, 1.f / (float)N_N, scB, shB);
    k_hupd<<<N_N * H / 1024, 256, 0, stream>>>(h, tb, scB, shB);
  }

  k_gemmM<<<N_N / 128, 256, 0, stream>>>(h, nullptr, WO1hi, WO1lo, bo1,
                                         nullptr, nullptr, 0, H, ta,
                                         statS + 6 * 256, statS + 6 * 256 + 128);
  k_bnfin<<<1, 128, 0, stream>>>(statS + 6 * 256, statS + 6 * 256 + 128,
                                 go1, beo1, 1.f / (float)N_N, scA, shA);
  k_head<<<B_N, 256, 0, stream>>>(ta, scA, shA, wo2, bo2, (float*)d_out);
}